// Round 13
// baseline (943.681 us; speedup 1.0000x reference)
//
#include <hip/hip_runtime.h>
#include <hip/hip_bf16.h>
#include <math.h>

#define DEVI __device__ __forceinline__

namespace {
constexpr int kL   = 1024;
constexpr int kDM  = 512;
constexpr int kDS  = 16;
constexpr int kDFF = 2048;
constexpr int kR   = 32;
constexpr int kDI  = 512;
constexpr int kB   = 16;
constexpr int kM   = kB * kL;     // 16384 rows
constexpr int kNC  = 32;          // scan chunks
constexpr int kCH  = kL / kNC;    // 32 steps per chunk
constexpr float kLOG2E = 1.4426950408889634f;
}

typedef __attribute__((ext_vector_type(8))) short short8;
typedef __attribute__((ext_vector_type(4))) float f32x4;

DEVI float silu_f(float x)     { return x / (1.f + __expf(-x)); }
DEVI float softplus_f(float x) { return fmaxf(x, 0.f) + log1pf(__expf(-fabsf(x))); }
DEVI float gelu_f(float x)     { return 0.5f * x * (1.f + erff(x * 0.70710678118654752f)); }

// raw hardware exp2 (v_exp_f32): 1 instruction, no libm wrapper
DEVI float fexp2(float x) {
    float r;
    asm("v_exp_f32 %0, %1" : "=v"(r) : "v"(x));
    return r;
}

DEVI unsigned short f2bf(float f) {
    unsigned int u = __float_as_uint(f);
    return (unsigned short)((u + 0x7fffu + ((u >> 16) & 1u)) >> 16);
}
DEVI float bf2f(unsigned short u) {
    return __uint_as_float(((unsigned int)u) << 16);
}
DEVI uint2 pack4(float4 v) {
    uint2 p;
    p.x = (unsigned int)f2bf(v.x) | ((unsigned int)f2bf(v.y) << 16);
    p.y = (unsigned int)f2bf(v.z) | ((unsigned int)f2bf(v.w) << 16);
    return p;
}

typedef const __attribute__((address_space(1))) unsigned int* gas1;
typedef __attribute__((address_space(3))) unsigned int* las3;
DEVI void gload16(const unsigned short* g, unsigned short* l) {
    __builtin_amdgcn_global_load_lds((gas1)g, (las3)l, 16, 0, 0);
}

// ---------------------------------------------------------------------------
// One-shot weight conversion f32 -> bf16 (6 segments).
// ---------------------------------------------------------------------------
struct WCvtArgs { const float* src[6]; unsigned int end[6]; };

__global__ __launch_bounds__(256) void cvt_weights_k(
    WCvtArgs a, unsigned short* __restrict__ dst)
{
    unsigned int i = (blockIdx.x * 256 + threadIdx.x) * 4;
    if (i >= a.end[5]) return;
    int j = 0;
    while (i >= a.end[j]) ++j;
    unsigned int base = j ? a.end[j - 1] : 0;
    float4 v = *(const float4*)&a.src[j][i - base];
    *(uint2*)&dst[i] = pack4(v);
}

__global__ __launch_bounds__(256) void init_x_k(
    const float* __restrict__ x, float* __restrict__ xo,
    unsigned short* __restrict__ xb)
{
    size_t i = (size_t)(blockIdx.x * 256 + threadIdx.x) * 4;
    float4 v = *(const float4*)&x[i];
    *(float4*)&xo[i] = v;
    *(uint2*)&xb[i] = pack4(v);
}

// ---------------------------------------------------------------------------
// bf16 MFMA GEMM (proven r4 structure): 128 x BN, BK=32, 4 waves, 2-phase.
// EPI: 0 plain (CT ushort/float), 1 bias+softplus (CT), 3 bias+gelu (bf16),
//      4 bias+add (f32), 5 plain f32 + bf16 aux cols<32. z-batched.
// ---------------------------------------------------------------------------
template <int EPI, int BN, typename CT>
__global__ __launch_bounds__(256) void gemm_bf16(
    const unsigned short* __restrict__ A, int lda, size_t zA,
    const unsigned short* __restrict__ W, size_t zW,
    CT* __restrict__ C, int ldc, size_t zC,
    const float* __restrict__ biasb, int zBias,
    const float* __restrict__ add,
    unsigned short* __restrict__ auxb, size_t zAux, int Kd)
{
    static_assert(BN == 64 || BN == 128, "");
    constexpr int NF = BN / 32;
    __shared__ alignas(16) unsigned short As[2][128 * 32];
    __shared__ alignas(16) unsigned short Ws[2][BN * 32];

    const int z = blockIdx.z;
    A += (size_t)z * zA; W += (size_t)z * zW; C += (size_t)z * zC;
    const float* bias = biasb ? biasb + (size_t)z * zBias : nullptr;
    unsigned short* aux = auxb ? auxb + (size_t)z * zAux : nullptr;

    const int gx = gridDim.x;
    int flat = blockIdx.y * gx + blockIdx.x;
    const int total = gx * gridDim.y;
    if ((total & 7) == 0) {
        int q = total >> 3;
        flat = (flat & 7) * q + (flat >> 3);
    }
    const int bx = flat % gx;
    const int by = flat / gx;

    const int tid  = threadIdx.x;
    const int lane = tid & 63;
    const int wv   = tid >> 6;
    const int wm   = wv >> 1;
    const int wn   = wv & 1;
    const int row0 = by * 128;
    const int col0 = bx * BN;

    f32x4 acc[4][NF];
#pragma unroll
    for (int m = 0; m < 4; ++m)
#pragma unroll
        for (int n = 0; n < NF; ++n) acc[m][n] = (f32x4){0.f, 0.f, 0.f, 0.f};

    const int sr  = tid >> 2;
    const int scw = (((tid & 3) ^ ((tid >> 3) & 3)) * 8);
    const unsigned short* Ag = A + (size_t)(row0 + sr) * lda + scw;
    const unsigned short* Wg = W + (size_t)(col0 + sr) * Kd + scw;

    auto stage = [&](int buf, int k0) {
        gload16(Ag + k0, &As[buf][tid * 8]);
        gload16(Ag + (size_t)64 * lda + k0, &As[buf][2048 + tid * 8]);
        gload16(Wg + k0, &Ws[buf][tid * 8]);
        if (BN == 128)
            gload16(Wg + (size_t)64 * Kd + k0, &Ws[buf][2048 + tid * 8]);
    };

    const int nt = Kd / 32;
    stage(0, 0);
    __syncthreads();

    const int fr  = lane & 15;
    const int sw8 = (((lane >> 4) ^ ((fr >> 1) & 3)) * 8);

    int cur = 0;
    for (int t = 0; t < nt; ++t) {
        if (t + 1 < nt) stage(cur ^ 1, (t + 1) * 32);
        short8 af[4], bf[NF];
#pragma unroll
        for (int m = 0; m < 4; ++m)
            af[m] = *(const short8*)&As[cur][(wm * 64 + m * 16 + fr) * 32 + sw8];
#pragma unroll
        for (int n = 0; n < NF; ++n)
            bf[n] = *(const short8*)&Ws[cur][(wn * (BN / 2) + n * 16 + fr) * 32 + sw8];
        __builtin_amdgcn_s_setprio(1);
#pragma unroll
        for (int m = 0; m < 4; ++m)
#pragma unroll
            for (int n = 0; n < NF; ++n)
                acc[m][n] = __builtin_amdgcn_mfma_f32_16x16x32_bf16(
                    af[m], bf[n], acc[m][n], 0, 0, 0);
        __builtin_amdgcn_s_setprio(0);
        __syncthreads();
        cur ^= 1;
    }

    const int cr = (lane >> 4) * 4;
#pragma unroll
    for (int m = 0; m < 4; ++m) {
#pragma unroll
        for (int n = 0; n < NF; ++n) {
            int cn = col0 + wn * (BN / 2) + n * 16 + fr;
#pragma unroll
            for (int r = 0; r < 4; ++r) {
                int rr = row0 + wm * 64 + m * 16 + cr + r;
                size_t idx = (size_t)rr * ldc + cn;
                float v = acc[m][n][r];
                if constexpr (EPI == 0) {
                    if constexpr (__is_same(CT, unsigned short)) C[idx] = f2bf(v);
                    else C[idx] = v;
                } else if constexpr (EPI == 1) {
                    float sp = softplus_f(v + bias[cn]);
                    if constexpr (__is_same(CT, unsigned short)) C[idx] = f2bf(sp);
                    else C[idx] = sp;
                } else if constexpr (EPI == 3) {
                    C[idx] = f2bf(gelu_f(v + bias[cn]));
                } else if constexpr (EPI == 4) {
                    C[idx] = v + bias[cn] + add[idx];
                } else {  // 5: f32 out + bf16 aux for cols < 32
                    C[idx] = v;
                    if (cn < 32) aux[(size_t)rr * 32 + cn] = f2bf(v);
                }
            }
        }
    }
}

// ---------------------------------------------------------------------------
// Sliding-window depthwise conv (K=4) + bias + silu.
// ---------------------------------------------------------------------------
__global__ __launch_bounds__(128) void conv_silu_k(
    const unsigned short* __restrict__ xz2, unsigned short* __restrict__ xcb,
    const float* __restrict__ wb, const float* __restrict__ biasb)
{
    const int task = blockIdx.x * 128 + threadIdx.x;
    const int g   = task & 63;
    const int c   = (task >> 6) & 31;
    const int b   = (task >> 11) & 15;
    const int dir = (task >> 15) & 1;
    const int d0  = g * 8;

    const unsigned short* xzd = xz2 + (size_t)dir * 1024 + (size_t)b * kL * 2048 + d0;
    unsigned short* xc = xcb + (size_t)dir * kM * kDI + (size_t)b * kL * kDI + d0;
    const float* w    = wb + (size_t)dir * 2048;
    const float* bias = biasb + (size_t)dir * 512;

    float wk[4][8];
#pragma unroll
    for (int k = 0; k < 4; ++k)
#pragma unroll
        for (int j = 0; j < 8; ++j)
            wk[k][j] = w[(d0 + j) * 4 + (dir ? 3 - k : k)];
    float bs[8];
#pragma unroll
    for (int j = 0; j < 8; ++j) bs[j] = bias[d0 + j];

    const int t0 = c * 32;
    const int rbase = dir ? t0 : t0 - 3;

    auto loadrow = [&](int t, float* o) {
        if (t < 0 || t >= kL) {
#pragma unroll
            for (int j = 0; j < 8; ++j) o[j] = 0.f;
            return;
        }
        uint4 p = *(const uint4*)&xzd[(size_t)t * 2048];
        o[0] = bf2f((unsigned short)(p.x & 0xffff));
        o[1] = bf2f((unsigned short)(p.x >> 16));
        o[2] = bf2f((unsigned short)(p.y & 0xffff));
        o[3] = bf2f((unsigned short)(p.y >> 16));
        o[4] = bf2f((unsigned short)(p.z & 0xffff));
        o[5] = bf2f((unsigned short)(p.z >> 16));
        o[6] = bf2f((unsigned short)(p.w & 0xffff));
        o[7] = bf2f((unsigned short)(p.w >> 16));
    };

    float x0[8], x1[8], x2[8];
    loadrow(rbase + 0, x0);
    loadrow(rbase + 1, x1);
    loadrow(rbase + 2, x2);

#pragma unroll 4
    for (int i = 0; i < 32; ++i) {
        float x3[8];
        loadrow(rbase + 3 + i, x3);
        unsigned short o[8];
#pragma unroll
        for (int j = 0; j < 8; ++j) {
            float v = bs[j];
            v = fmaf(wk[0][j], x0[j], v);
            v = fmaf(wk[1][j], x1[j], v);
            v = fmaf(wk[2][j], x2[j], v);
            v = fmaf(wk[3][j], x3[j], v);
            o[j] = f2bf(silu_f(v));
        }
        *(uint4*)&xc[(size_t)(t0 + i) * kDI] = *(uint4*)o;
#pragma unroll
        for (int j = 0; j < 8; ++j) { x0[j] = x1[j]; x1[j] = x2[j]; x2[j] = x3[j]; }
    }
}

// ---------------------------------------------------------------------------
// Chunked selective scan, both dirs (blockIdx.y = dir). dt bf16.
// B staged to LDS once per block (wave-uniform broadcast reads).
// ---------------------------------------------------------------------------
__global__ __launch_bounds__(256) void scan_chunk(
    const unsigned short* __restrict__ dtb2, const unsigned short* __restrict__ xcb2,
    const float* __restrict__ dbl2, const float* __restrict__ A_logb,
    float* __restrict__ S2, float* __restrict__ sdt2)
{
    int dir = blockIdx.y;
    const unsigned short* dtb = dtb2 + (size_t)dir * kM * kDI;
    const unsigned short* xcb = xcb2 + (size_t)dir * kM * kDI;
    const float* dbl = dbl2 + (size_t)dir * kM * 64;
    const float* A_log = A_logb + (size_t)dir * 8192;
    float* S   = S2 + (size_t)dir * (kB * kNC * kDS * kDI);
    float* sdt = sdt2 + (size_t)dir * (kB * kNC * kDI);

    int blk  = blockIdx.x;
    int dblk = blk & 1;
    int c    = (blk >> 1) & (kNC - 1);
    int b    = blk >> 6;
    int d    = dblk * 256 + threadIdx.x;

    // stage this chunk's B[32 steps][16] into LDS (each thread: 2 floats)
    __shared__ float blds[32][16];
    {
        int i = threadIdx.x >> 3, q = (threadIdx.x & 7) * 2;
        int t = dir ? (kL - 1 - (c * kCH + i)) : (c * kCH + i);
        *(float2*)&blds[i][q] =
            *(const float2*)&dbl[(size_t)(b * kL + t) * 64 + kR + q];
    }
    __syncthreads();

    const float* al = A_log + d * kDS;
    float A2[16];
#pragma unroll
    for (int s = 0; s < 16; ++s) A2[s] = -__expf(al[s]) * kLOG2E;

    float h[16];
#pragma unroll
    for (int s = 0; s < 16; ++s) h[s] = 0.f;
    float sum = 0.f;

#pragma unroll 2
    for (int i = 0; i < kCH; ++i) {
        int p   = c * kCH + i;
        int t   = dir ? (kL - 1 - p) : p;
        int row = b * kL + t;
        float dt = bf2f(dtb[(size_t)row * kDI + d]);
        float xv = bf2f(xcb[(size_t)row * kDI + d]);
        sum += dt;
        float dx = dt * xv;
        const float4* bp = (const float4*)&blds[i][0];
        float4 b0 = bp[0], b1 = bp[1], b2 = bp[2], b3 = bp[3];
        float Bv[16] = {b0.x, b0.y, b0.z, b0.w, b1.x, b1.y, b1.z, b1.w,
                        b2.x, b2.y, b2.z, b2.w, b3.x, b3.y, b3.z, b3.w};
#pragma unroll
        for (int s = 0; s < 16; ++s) {
            float q = fexp2(dt * A2[s]);
            h[s] = fmaf(q, h[s], dx * Bv[s]);
        }
    }
    size_t base = (size_t)(b * kNC + c) * kDS * kDI + d;
#pragma unroll
    for (int s = 0; s < 16; ++s) S[base + s * kDI] = h[s];
    sdt[(size_t)(b * kNC + c) * kDI + d] = sum;
}

// ---------------------------------------------------------------------------
// Carry scan: one thread per (b,d,s) recurrence; h0 written in-place over S.
// ---------------------------------------------------------------------------
__global__ __launch_bounds__(256) void scan_carry(
    float* __restrict__ S2, const float* __restrict__ sdt2,
    const float* __restrict__ A_logb)
{
    int dir = blockIdx.y;
    float* S = S2 + (size_t)dir * (kB * kNC * kDS * kDI);
    const float* sdt = sdt2 + (size_t)dir * (kB * kNC * kDI);
    const float* A_log = A_logb + (size_t)dir * 8192;

    int g = blockIdx.x * 256 + threadIdx.x;   // 0..131071
    int d = g & (kDI - 1);
    int s = (g >> 9) & 15;
    int b = g >> 13;

    float A2 = -__expf(A_log[d * kDS + s]) * kLOG2E;
    float h = 0.f;
#pragma unroll
    for (int c = 0; c < kNC; ++c) {
        size_t base = ((size_t)(b * kNC + c) * kDS + s) * kDI + d;
        float sv = S[base];
        float sd = sdt[(size_t)(b * kNC + c) * kDI + d];
        S[base] = h;                          // h0 in-place
        h = fmaf(fexp2(sd * A2), h, sv);
    }
}

// ---------------------------------------------------------------------------
// Emit scan: B and C staged to LDS once per block (broadcast reads).
// ---------------------------------------------------------------------------
__global__ __launch_bounds__(256) void scan_emit(
    const unsigned short* __restrict__ dtb2, const unsigned short* __restrict__ xcb2,
    const float* __restrict__ dbl2, const float* __restrict__ A_logb,
    const float* __restrict__ h0v2, const float* __restrict__ Dpb,
    const unsigned short* __restrict__ xz2, unsigned short* __restrict__ yb2)
{
    int dir = blockIdx.y;
    const unsigned short* dtb = dtb2 + (size_t)dir * kM * kDI;
    const unsigned short* xcb = xcb2 + (size_t)dir * kM * kDI;
    const float* dbl = dbl2 + (size_t)dir * kM * 64;
    const float* A_log = A_logb + (size_t)dir * 8192;
    const float* h0v = h0v2 + (size_t)dir * (kB * kNC * kDS * kDI);
    const float* Dp = Dpb + (size_t)dir * 512;
    const unsigned short* zg = xz2 + (size_t)dir * 1024 + 512;
    unsigned short* yb = yb2 + (size_t)dir * kM * kDI;

    int blk  = blockIdx.x;
    int dblk = blk & 1;
    int c    = (blk >> 1) & (kNC - 1);
    int b    = blk >> 6;
    int d    = dblk * 256 + threadIdx.x;

    // stage this chunk's [B|C][32 steps][32] into LDS (each thread: 4 floats)
    __shared__ float bclds[32][32];
    {
        int i = threadIdx.x >> 3, q = (threadIdx.x & 7) * 4;
        int t = dir ? (kL - 1 - (c * kCH + i)) : (c * kCH + i);
        *(float4*)&bclds[i][q] =
            *(const float4*)&dbl[(size_t)(b * kL + t) * 64 + kR + q];
    }
    __syncthreads();

    const float* al = A_log + d * kDS;
    float A2[16];
#pragma unroll
    for (int s = 0; s < 16; ++s) A2[s] = -__expf(al[s]) * kLOG2E;
    float Dd = Dp[d];

    size_t hbase = (size_t)(b * kNC + c) * kDS * kDI + d;
    float h[16];
#pragma unroll
    for (int s = 0; s < 16; ++s) h[s] = h0v[hbase + s * kDI];

#pragma unroll 2
    for (int i = 0; i < kCH; ++i) {
        int p   = c * kCH + i;
        int t   = dir ? (kL - 1 - p) : p;
        int row = b * kL + t;
        float dt = bf2f(dtb[(size_t)row * kDI + d]);
        float xv = bf2f(xcb[(size_t)row * kDI + d]);
        float dx = dt * xv;
        const float4* bp = (const float4*)&bclds[i][0];
        const float4* cp = (const float4*)&bclds[i][16];
        float4 b0 = bp[0], b1 = bp[1], b2 = bp[2], b3 = bp[3];
        float4 c0 = cp[0], c1 = cp[1], c2 = cp[2], c3 = cp[3];
        float Bv[16] = {b0.x, b0.y, b0.z, b0.w, b1.x, b1.y, b1.z, b1.w,
                        b2.x, b2.y, b2.z, b2.w, b3.x, b3.y, b3.z, b3.w};
        float Cv[16] = {c0.x, c0.y, c0.z, c0.w, c1.x, c1.y, c1.z, c1.w,
                        c2.x, c2.y, c2.z, c2.w, c3.x, c3.y, c3.z, c3.w};
        float y = 0.f;
#pragma unroll
        for (int s = 0; s < 16; ++s) {
            float q = fexp2(dt * A2[s]);
            h[s] = fmaf(q, h[s], dx * Bv[s]);
            y = fmaf(h[s], Cv[s], y);
        }
        y += xv * Dd;
        float z = bf2f(zg[(size_t)row * 2048 + d]);
        yb[(size_t)row * kDI + d] = f2bf(y * silu_f(z));
    }
}

// ---------------------------------------------------------------------------
// LayerNorm over rows of 512; optional 2 bf16 add-inputs and bf16 copy.
// ---------------------------------------------------------------------------
__global__ __launch_bounds__(128) void ln_k(
    const float* __restrict__ in, const unsigned short* __restrict__ a0,
    const unsigned short* __restrict__ a1,
    const float* __restrict__ g, const float* __restrict__ bb,
    float* __restrict__ out, unsigned short* __restrict__ outbf)
{
    int row = blockIdx.x;
    int tid = threadIdx.x;
    size_t off = (size_t)row * kDM + tid * 4;
    float4 v = *(const float4*)&in[off];
    if (a0) {
        uint2 u0 = *(const uint2*)&a0[off];
        uint2 u1 = *(const uint2*)&a1[off];
        v.x += bf2f((unsigned short)(u0.x & 0xffff)) + bf2f((unsigned short)(u1.x & 0xffff));
        v.y += bf2f((unsigned short)(u0.x >> 16))    + bf2f((unsigned short)(u1.x >> 16));
        v.z += bf2f((unsigned short)(u0.y & 0xffff)) + bf2f((unsigned short)(u1.y & 0xffff));
        v.w += bf2f((unsigned short)(u0.y >> 16))    + bf2f((unsigned short)(u1.y >> 16));
    }
    float s1 = v.x + v.y + v.z + v.w;
    float s2 = v.x * v.x + v.y * v.y + v.z * v.z + v.w * v.w;
#pragma unroll
    for (int o = 32; o >= 1; o >>= 1) {
        s1 += __shfl_xor(s1, o);
        s2 += __shfl_xor(s2, o);
    }
    __shared__ float red[4];
    if ((tid & 63) == 0) { red[(tid >> 6) * 2] = s1; red[(tid >> 6) * 2 + 1] = s2; }
    __syncthreads();
    s1 = red[0] + red[2];
    s2 = red[1] + red[3];
    float mu  = s1 * (1.f / kDM);
    float var = s2 * (1.f / kDM) - mu * mu;
    float rs  = rsqrtf(var + 1e-5f);
    int cn = tid * 4;
    float4 gv = *(const float4*)&g[cn];
    float4 bv = *(const float4*)&bb[cn];
    float4 o;
    o.x = (v.x - mu) * rs * gv.x + bv.x;
    o.y = (v.y - mu) * rs * gv.y + bv.y;
    o.z = (v.z - mu) * rs * gv.z + bv.z;
    o.w = (v.w - mu) * rs * gv.w + bv.w;
    *(float4*)&out[off] = o;
    if (outbf)
        *(uint2*)&outbf[off] = pack4(o);
}

// ---------------------------------------------------------------------------
extern "C" void kernel_launch(void* const* d_in, const int* in_sizes, int n_in,
                              void* d_out, int out_size, void* d_ws, size_t ws_size,
                              hipStream_t stream)
{
    const float* x_in    = (const float*)d_in[0];
    const float* in_w    = (const float*)d_in[1];
    const float* conv_w  = (const float*)d_in[2];
    const float* conv_b  = (const float*)d_in[3];
    const float* xproj_w = (const float*)d_in[4];
    const float* dt_w    = (const float*)d_in[5];
    const float* dt_b    = (const float*)d_in[6];
    const float* A_log   = (const float*)d_in[7];
    const float* Dp      = (const float*)d_in[8];
    const float* out_w   = (const float*)d_in[9];
    const float* ff_w1   = (const float*)d_in[10];
    const float* ff_b1   = (const float*)d_in[11];
    const float* ff_w2   = (const float*)d_in[12];
    const float* ff_b2   = (const float*)d_in[13];
    const float* ln1_g   = (const float*)d_in[14];
    const float* ln1_b   = (const float*)d_in[15];
    const float* ln2_g   = (const float*)d_in[16];
    const float* ln2_b   = (const float*)d_in[17];
    const float* lnf_g   = (const float*)d_in[18];
    const float* lnf_b   = (const float*)d_in[19];

    float* ws = (float*)d_ws;
    unsigned short* wsb = (unsigned short*)d_ws;

    // bf16 weights (bf16-elem offsets into wsb)
    unsigned short* wb_in  = wsb;                 // in_w   [0, 2097152)
    unsigned short* wb_xp  = wsb + 2097152;       // xproj  [.., 2228224)
    unsigned short* wb_out = wsb + 2228224;       // out_w  [.., 3276800)
    unsigned short* wb_f1  = wsb + 3276800;       // ff_w1  [.., 5373952)
    unsigned short* wb_f2  = wsb + 5373952;       // ff_w2  [.., 7471104)
    unsigned short* wb_dt  = wsb + 7471104;       // dt_w   [.., 7536640)

    constexpr size_t A0 = 3768320;                // f32-word offset of arena
    unsigned short* xbf  = (unsigned short*)(ws + A0);                  // 4.19M w
    unsigned short* xz2  = (unsigned short*)(ws + A0 + 4194304);        // 16.78M w
    unsigned short* xcb2 = (unsigned short*)(ws + A0 + 20971520);       // 8.39M w
    unsigned short* yb2  = (unsigned short*)(ws + A0 + 29360128);       // 8.39M w
    float*          Sb2  = ws + A0 + 37748736;                          // 8.39M w (S/h0)
    unsigned short* dtb2 = (unsigned short*)(ws + A0 + 46137344);       // 8.39M w
    float*          dbl2 = ws + A0 + 54525952;                          // 2.10M w
    unsigned short* dtin2= (unsigned short*)(ws + A0 + 56623104);       // 0.52M w
    float*          sdt2 = ws + A0 + 57147392;                          // 0.52M w
    // out-proj bf16 outputs alias scan scratch (S/h0 dead after scan_emit)
    unsigned short* o2   = (unsigned short*)(ws + A0 + 37748736);       // 8M w as bf16
    // FFN-phase aliases (mamba arena dead)
    float*          xn   = ws + A0;                                     // 8.39M w
    unsigned short* xnbf = (unsigned short*)(ws + A0 + 8388608);        // 4.19M w
    unsigned short* Hb   = (unsigned short*)(ws + A0 + 12582912);       // 16.78M w
    float*          t2   = ws + A0 + 29360128;                          // 8.39M w

    float* xcur = (float*)d_out;
    dim3 thr(256);

    WCvtArgs wa;
    wa.src[0] = in_w;    wa.end[0] = 2097152;
    wa.src[1] = xproj_w; wa.end[1] = 2228224;
    wa.src[2] = out_w;   wa.end[2] = 3276800;
    wa.src[3] = ff_w1;   wa.end[3] = 5373952;
    wa.src[4] = ff_w2;   wa.end[4] = 7471104;
    wa.src[5] = dt_w;    wa.end[5] = 7536640;
    cvt_weights_k<<<dim3(7536640 / 1024), thr, 0, stream>>>(wa, wsb);
    init_x_k<<<dim3(8192), thr, 0, stream>>>(x_in, xcur, xbf);

    for (int e = 0; e < 2; ++e) {
        // in-proj (both dirs fused): (kM x 512) @ (2048 x 512)^T -> xz2 bf16
        gemm_bf16<0, 128, unsigned short><<<dim3(16, 128), thr, 0, stream>>>(
            xbf, 512, 0, wb_in + (size_t)e * 1048576, 0, xz2, 2048, 0,
            nullptr, 0, nullptr, nullptr, 0, 512);
        // conv + silu (both dirs, sliding window)
        conv_silu_k<<<dim3(512), dim3(128), 0, stream>>>(
            xz2, xcb2, conv_w + (size_t)e * 4096, conv_b + (size_t)e * 1024);
        // x-proj (both dirs): -> dbl f32 + dtin bf16
        gemm_bf16<5, 64, float><<<dim3(1, 128, 2), thr, 0, stream>>>(
            xcb2, 512, (size_t)kM * 512, wb_xp + (size_t)e * 65536, 32768,
            dbl2, 64, (size_t)kM * 64, nullptr, 0, nullptr,
            dtin2, (size_t)kM * 32, 512);
        // dt-proj (both dirs): softplus -> dtb2 bf16
        gemm_bf16<1, 128, unsigned short><<<dim3(4, 128, 2), thr, 0, stream>>>(
            dtin2, 32, (size_t)kM * 32, wb_dt + (size_t)e * 32768, 16384,
            dtb2, 512, (size_t)kM * 512, dt_b + (size_t)e * 1024, 512,
            nullptr, nullptr, 0, 32);
        // scans (both dirs)
        scan_chunk<<<dim3(kB * kNC * 2, 2), thr, 0, stream>>>(
            dtb2, xcb2, dbl2, A_log + (size_t)e * 16384, Sb2, sdt2);
        scan_carry<<<dim3(512, 2), thr, 0, stream>>>(
            Sb2, sdt2, A_log + (size_t)e * 16384);
        scan_emit<<<dim3(kB * kNC * 2, 2), thr, 0, stream>>>(
            dtb2, xcb2, dbl2, A_log + (size_t)e * 16384, Sb2,
            Dp + (size_t)e * 1024, xz2, yb2);
        // out-proj (both dirs) -> o2 bf16 (separate buffers; LN1 adds)
        gemm_bf16<0, 128, unsigned short><<<dim3(4, 128, 2), thr, 0, stream>>>(
            yb2, 512, (size_t)kM * 512, wb_out + (size_t)e * 524288, 262144,
            o2, 512, (size_t)kM * 512, nullptr, 0, nullptr, nullptr, 0, 512);
        // LN1: normalize (xcur + o0 + o1) -> xn f32 + xnbf bf16
        ln_k<<<dim3(kM), dim3(128), 0, stream>>>(
            xcur, o2, o2 + (size_t)kM * 512,
            ln1_g + e * kDM, ln1_b + e * kDM, xn, xnbf);
        // FFN1: gelu(xn @ w1^T + b1) -> Hb bf16
        gemm_bf16<3, 128, unsigned short><<<dim3(16, 128), thr, 0, stream>>>(
            xnbf, 512, 0, wb_f1 + (size_t)e * 1048576, 0, Hb, 2048, 0,
            ff_b1 + (size_t)e * kDFF, 0, nullptr, nullptr, 0, 512);
        // FFN2: Hb @ w2^T + b2 + xn -> t2 f32
        gemm_bf16<4, 128, float><<<dim3(4, 128), thr, 0, stream>>>(
            Hb, 2048, 0, wb_f2 + (size_t)e * 1048576, 0, t2, 512, 0,
            ff_b2 + (size_t)e * kDM, 0, xn, nullptr, 0, 2048);
        // LN2 -> xcur (+ bf16 snapshot for next layer)
        ln_k<<<dim3(kM), dim3(128), 0, stream>>>(
            t2, nullptr, nullptr, ln2_g + e * kDM, ln2_b + e * kDM, xcur,
            e == 0 ? xbf : nullptr);
    }
    ln_k<<<dim3(kM), dim3(128), 0, stream>>>(
        xcur, nullptr, nullptr, lnf_g, lnf_b, xcur, nullptr);
}

// Round 14
// 940.649 us; speedup vs baseline: 1.0032x; 1.0032x over previous
//
#include <hip/hip_runtime.h>
#include <hip/hip_bf16.h>
#include <math.h>

#define DEVI __device__ __forceinline__

namespace {
constexpr int kL   = 1024;
constexpr int kDM  = 512;
constexpr int kDS  = 16;
constexpr int kDFF = 2048;
constexpr int kR   = 32;
constexpr int kDI  = 512;
constexpr int kB   = 16;
constexpr int kM   = kB * kL;     // 16384 rows
constexpr int kNC  = 32;          // scan chunks
constexpr int kCH  = kL / kNC;    // 32 steps per chunk
constexpr float kLOG2E = 1.4426950408889634f;
}

typedef __attribute__((ext_vector_type(8))) short short8;
typedef __attribute__((ext_vector_type(4))) float f32x4;

DEVI float silu_f(float x)     { return x / (1.f + __expf(-x)); }
DEVI float softplus_f(float x) { return fmaxf(x, 0.f) + log1pf(__expf(-fabsf(x))); }
DEVI float gelu_f(float x)     { return 0.5f * x * (1.f + erff(x * 0.70710678118654752f)); }

// raw hardware exp2 (v_exp_f32): 1 instruction, no libm wrapper
DEVI float fexp2(float x) {
    float r;
    asm("v_exp_f32 %0, %1" : "=v"(r) : "v"(x));
    return r;
}

DEVI unsigned short f2bf(float f) {
    unsigned int u = __float_as_uint(f);
    return (unsigned short)((u + 0x7fffu + ((u >> 16) & 1u)) >> 16);
}
DEVI float bf2f(unsigned short u) {
    return __uint_as_float(((unsigned int)u) << 16);
}
DEVI uint2 pack4(float4 v) {
    uint2 p;
    p.x = (unsigned int)f2bf(v.x) | ((unsigned int)f2bf(v.y) << 16);
    p.y = (unsigned int)f2bf(v.z) | ((unsigned int)f2bf(v.w) << 16);
    return p;
}

typedef const __attribute__((address_space(1))) unsigned int* gas1;
typedef __attribute__((address_space(3))) unsigned int* las3;
DEVI void gload16(const unsigned short* g, unsigned short* l) {
    __builtin_amdgcn_global_load_lds((gas1)g, (las3)l, 16, 0, 0);
}

// ---------------------------------------------------------------------------
// One-shot weight conversion f32 -> bf16 (6 segments).
// ---------------------------------------------------------------------------
struct WCvtArgs { const float* src[6]; unsigned int end[6]; };

__global__ __launch_bounds__(256) void cvt_weights_k(
    WCvtArgs a, unsigned short* __restrict__ dst)
{
    unsigned int i = (blockIdx.x * 256 + threadIdx.x) * 4;
    if (i >= a.end[5]) return;
    int j = 0;
    while (i >= a.end[j]) ++j;
    unsigned int base = j ? a.end[j - 1] : 0;
    float4 v = *(const float4*)&a.src[j][i - base];
    *(uint2*)&dst[i] = pack4(v);
}

__global__ __launch_bounds__(256) void init_x_k(
    const float* __restrict__ x, float* __restrict__ xo,
    unsigned short* __restrict__ xb)
{
    size_t i = (size_t)(blockIdx.x * 256 + threadIdx.x) * 4;
    float4 v = *(const float4*)&x[i];
    *(float4*)&xo[i] = v;
    *(uint2*)&xb[i] = pack4(v);
}

// ---------------------------------------------------------------------------
// bf16 MFMA GEMM: 128 x BN, BK=32, 4 waves, double-buffered LDS with
// COUNTED-vmcnt pipeline (T4): {vmcnt(LPT) -> s_barrier -> ds_read+MFMA ->
// s_barrier -> stage(t+2)}. Prefetch loads stay in flight across barriers
// (never drained to 0 in the main loop). 32 KB LDS -> 2-3 blocks/CU keep
// inter-block overlap. Hazards: buf-t read only after per-wave vmcnt(LPT)
// (in-order retire => own t-loads done) + barrier (extends to all waves);
// buf re-write only after barrier #2 (all ds_reads complete).
// EPI: 0 plain (CT ushort/float), 1 bias+softplus (CT), 3 bias+gelu (bf16),
//      4 bias+add (f32), 5 plain f32 + bf16 aux cols<32. z-batched.
// ---------------------------------------------------------------------------
template <int EPI, int BN, typename CT>
__global__ __launch_bounds__(256) void gemm_bf16(
    const unsigned short* __restrict__ A, int lda, size_t zA,
    const unsigned short* __restrict__ W, size_t zW,
    CT* __restrict__ C, int ldc, size_t zC,
    const float* __restrict__ biasb, int zBias,
    const float* __restrict__ add,
    unsigned short* __restrict__ auxb, size_t zAux, int Kd)
{
    static_assert(BN == 64 || BN == 128, "");
    constexpr int NF = BN / 32;
    __shared__ alignas(16) unsigned short As[2][128 * 32];
    __shared__ alignas(16) unsigned short Ws[2][BN * 32];

    const int z = blockIdx.z;
    A += (size_t)z * zA; W += (size_t)z * zW; C += (size_t)z * zC;
    const float* bias = biasb ? biasb + (size_t)z * zBias : nullptr;
    unsigned short* aux = auxb ? auxb + (size_t)z * zAux : nullptr;

    const int gx = gridDim.x;
    int flat = blockIdx.y * gx + blockIdx.x;
    const int total = gx * gridDim.y;
    if ((total & 7) == 0) {
        int q = total >> 3;
        flat = (flat & 7) * q + (flat >> 3);
    }
    const int bx = flat % gx;
    const int by = flat / gx;

    const int tid  = threadIdx.x;
    const int lane = tid & 63;
    const int wv   = tid >> 6;
    const int wm   = wv >> 1;
    const int wn   = wv & 1;
    const int row0 = by * 128;
    const int col0 = bx * BN;

    f32x4 acc[4][NF];
#pragma unroll
    for (int m = 0; m < 4; ++m)
#pragma unroll
        for (int n = 0; n < NF; ++n) acc[m][n] = (f32x4){0.f, 0.f, 0.f, 0.f};

    const int sr  = tid >> 2;
    const int scw = (((tid & 3) ^ ((tid >> 3) & 3)) * 8);
    const unsigned short* Ag = A + (size_t)(row0 + sr) * lda + scw;
    const unsigned short* Wg = W + (size_t)(col0 + sr) * Kd + scw;

    auto stage = [&](int buf, int k0) {
        gload16(Ag + k0, &As[buf][tid * 8]);
        gload16(Ag + (size_t)64 * lda + k0, &As[buf][2048 + tid * 8]);
        gload16(Wg + k0, &Ws[buf][tid * 8]);
        if (BN == 128)
            gload16(Wg + (size_t)64 * Kd + k0, &Ws[buf][2048 + tid * 8]);
    };

    const int nt = Kd / 32;
    stage(0, 0);
    if (nt > 1) stage(1, 32);

    const int fr  = lane & 15;
    const int sw8 = (((lane >> 4) ^ ((fr >> 1) & 3)) * 8);

    for (int t = 0; t < nt; ++t) {
        const int cur = t & 1;
        // counted-vmcnt handshake: retire own tile-t loads, keep t+1 in flight
        if (t + 1 < nt) {
            if constexpr (BN == 128) asm volatile("s_waitcnt vmcnt(4)" ::: "memory");
            else                     asm volatile("s_waitcnt vmcnt(3)" ::: "memory");
        } else {
            asm volatile("s_waitcnt vmcnt(0)" ::: "memory");
        }
        __builtin_amdgcn_sched_barrier(0);
        __builtin_amdgcn_s_barrier();
        __builtin_amdgcn_sched_barrier(0);

        short8 af[4], bf[NF];
#pragma unroll
        for (int m = 0; m < 4; ++m)
            af[m] = *(const short8*)&As[cur][(wm * 64 + m * 16 + fr) * 32 + sw8];
#pragma unroll
        for (int n = 0; n < NF; ++n)
            bf[n] = *(const short8*)&Ws[cur][(wn * (BN / 2) + n * 16 + fr) * 32 + sw8];
        __builtin_amdgcn_s_setprio(1);
#pragma unroll
        for (int m = 0; m < 4; ++m)
#pragma unroll
            for (int n = 0; n < NF; ++n)
                acc[m][n] = __builtin_amdgcn_mfma_f32_16x16x32_bf16(
                    af[m], bf[n], acc[m][n], 0, 0, 0);
        __builtin_amdgcn_s_setprio(0);

        __builtin_amdgcn_sched_barrier(0);
        __builtin_amdgcn_s_barrier();
        __builtin_amdgcn_sched_barrier(0);
        if (t + 2 < nt) stage(cur, (t + 2) * 32);
    }

    const int cr = (lane >> 4) * 4;
#pragma unroll
    for (int m = 0; m < 4; ++m) {
#pragma unroll
        for (int n = 0; n < NF; ++n) {
            int cn = col0 + wn * (BN / 2) + n * 16 + fr;
#pragma unroll
            for (int r = 0; r < 4; ++r) {
                int rr = row0 + wm * 64 + m * 16 + cr + r;
                size_t idx = (size_t)rr * ldc + cn;
                float v = acc[m][n][r];
                if constexpr (EPI == 0) {
                    if constexpr (__is_same(CT, unsigned short)) C[idx] = f2bf(v);
                    else C[idx] = v;
                } else if constexpr (EPI == 1) {
                    float sp = softplus_f(v + bias[cn]);
                    if constexpr (__is_same(CT, unsigned short)) C[idx] = f2bf(sp);
                    else C[idx] = sp;
                } else if constexpr (EPI == 3) {
                    C[idx] = f2bf(gelu_f(v + bias[cn]));
                } else if constexpr (EPI == 4) {
                    C[idx] = v + bias[cn] + add[idx];
                } else {  // 5: f32 out + bf16 aux for cols < 32
                    C[idx] = v;
                    if (cn < 32) aux[(size_t)rr * 32 + cn] = f2bf(v);
                }
            }
        }
    }
}

// ---------------------------------------------------------------------------
// Sliding-window depthwise conv (K=4) + bias + silu.
// ---------------------------------------------------------------------------
__global__ __launch_bounds__(128) void conv_silu_k(
    const unsigned short* __restrict__ xz2, unsigned short* __restrict__ xcb,
    const float* __restrict__ wb, const float* __restrict__ biasb)
{
    const int task = blockIdx.x * 128 + threadIdx.x;
    const int g   = task & 63;
    const int c   = (task >> 6) & 31;
    const int b   = (task >> 11) & 15;
    const int dir = (task >> 15) & 1;
    const int d0  = g * 8;

    const unsigned short* xzd = xz2 + (size_t)dir * 1024 + (size_t)b * kL * 2048 + d0;
    unsigned short* xc = xcb + (size_t)dir * kM * kDI + (size_t)b * kL * kDI + d0;
    const float* w    = wb + (size_t)dir * 2048;
    const float* bias = biasb + (size_t)dir * 512;

    float wk[4][8];
#pragma unroll
    for (int k = 0; k < 4; ++k)
#pragma unroll
        for (int j = 0; j < 8; ++j)
            wk[k][j] = w[(d0 + j) * 4 + (dir ? 3 - k : k)];
    float bs[8];
#pragma unroll
    for (int j = 0; j < 8; ++j) bs[j] = bias[d0 + j];

    const int t0 = c * 32;
    const int rbase = dir ? t0 : t0 - 3;

    auto loadrow = [&](int t, float* o) {
        if (t < 0 || t >= kL) {
#pragma unroll
            for (int j = 0; j < 8; ++j) o[j] = 0.f;
            return;
        }
        uint4 p = *(const uint4*)&xzd[(size_t)t * 2048];
        o[0] = bf2f((unsigned short)(p.x & 0xffff));
        o[1] = bf2f((unsigned short)(p.x >> 16));
        o[2] = bf2f((unsigned short)(p.y & 0xffff));
        o[3] = bf2f((unsigned short)(p.y >> 16));
        o[4] = bf2f((unsigned short)(p.z & 0xffff));
        o[5] = bf2f((unsigned short)(p.z >> 16));
        o[6] = bf2f((unsigned short)(p.w & 0xffff));
        o[7] = bf2f((unsigned short)(p.w >> 16));
    };

    float x0[8], x1[8], x2[8];
    loadrow(rbase + 0, x0);
    loadrow(rbase + 1, x1);
    loadrow(rbase + 2, x2);

#pragma unroll 4
    for (int i = 0; i < 32; ++i) {
        float x3[8];
        loadrow(rbase + 3 + i, x3);
        unsigned short o[8];
#pragma unroll
        for (int j = 0; j < 8; ++j) {
            float v = bs[j];
            v = fmaf(wk[0][j], x0[j], v);
            v = fmaf(wk[1][j], x1[j], v);
            v = fmaf(wk[2][j], x2[j], v);
            v = fmaf(wk[3][j], x3[j], v);
            o[j] = f2bf(silu_f(v));
        }
        *(uint4*)&xc[(size_t)(t0 + i) * kDI] = *(uint4*)o;
#pragma unroll
        for (int j = 0; j < 8; ++j) { x0[j] = x1[j]; x1[j] = x2[j]; x2[j] = x3[j]; }
    }
}

// ---------------------------------------------------------------------------
// Chunked selective scan, both dirs (blockIdx.y = dir). dt bf16.
// B staged to LDS once per block (wave-uniform broadcast reads).
// ---------------------------------------------------------------------------
__global__ __launch_bounds__(256) void scan_chunk(
    const unsigned short* __restrict__ dtb2, const unsigned short* __restrict__ xcb2,
    const float* __restrict__ dbl2, const float* __restrict__ A_logb,
    float* __restrict__ S2, float* __restrict__ sdt2)
{
    int dir = blockIdx.y;
    const unsigned short* dtb = dtb2 + (size_t)dir * kM * kDI;
    const unsigned short* xcb = xcb2 + (size_t)dir * kM * kDI;
    const float* dbl = dbl2 + (size_t)dir * kM * 64;
    const float* A_log = A_logb + (size_t)dir * 8192;
    float* S   = S2 + (size_t)dir * (kB * kNC * kDS * kDI);
    float* sdt = sdt2 + (size_t)dir * (kB * kNC * kDI);

    int blk  = blockIdx.x;
    int dblk = blk & 1;
    int c    = (blk >> 1) & (kNC - 1);
    int b    = blk >> 6;
    int d    = dblk * 256 + threadIdx.x;

    // stage this chunk's B[32 steps][16] into LDS (each thread: 2 floats)
    __shared__ float blds[32][16];
    {
        int i = threadIdx.x >> 3, q = (threadIdx.x & 7) * 2;
        int t = dir ? (kL - 1 - (c * kCH + i)) : (c * kCH + i);
        *(float2*)&blds[i][q] =
            *(const float2*)&dbl[(size_t)(b * kL + t) * 64 + kR + q];
    }
    __syncthreads();

    const float* al = A_log + d * kDS;
    float A2[16];
#pragma unroll
    for (int s = 0; s < 16; ++s) A2[s] = -__expf(al[s]) * kLOG2E;

    float h[16];
#pragma unroll
    for (int s = 0; s < 16; ++s) h[s] = 0.f;
    float sum = 0.f;

#pragma unroll 2
    for (int i = 0; i < kCH; ++i) {
        int p   = c * kCH + i;
        int t   = dir ? (kL - 1 - p) : p;
        int row = b * kL + t;
        float dt = bf2f(dtb[(size_t)row * kDI + d]);
        float xv = bf2f(xcb[(size_t)row * kDI + d]);
        sum += dt;
        float dx = dt * xv;
        const float4* bp = (const float4*)&blds[i][0];
        float4 b0 = bp[0], b1 = bp[1], b2 = bp[2], b3 = bp[3];
        float Bv[16] = {b0.x, b0.y, b0.z, b0.w, b1.x, b1.y, b1.z, b1.w,
                        b2.x, b2.y, b2.z, b2.w, b3.x, b3.y, b3.z, b3.w};
#pragma unroll
        for (int s = 0; s < 16; ++s) {
            float q = fexp2(dt * A2[s]);
            h[s] = fmaf(q, h[s], dx * Bv[s]);
        }
    }
    size_t base = (size_t)(b * kNC + c) * kDS * kDI + d;
#pragma unroll
    for (int s = 0; s < 16; ++s) S[base + s * kDI] = h[s];
    sdt[(size_t)(b * kNC + c) * kDI + d] = sum;
}

// ---------------------------------------------------------------------------
// Carry scan: one thread per (b,d,s) recurrence; h0 written in-place over S.
// ---------------------------------------------------------------------------
__global__ __launch_bounds__(256) void scan_carry(
    float* __restrict__ S2, const float* __restrict__ sdt2,
    const float* __restrict__ A_logb)
{
    int dir = blockIdx.y;
    float* S = S2 + (size_t)dir * (kB * kNC * kDS * kDI);
    const float* sdt = sdt2 + (size_t)dir * (kB * kNC * kDI);
    const float* A_log = A_logb + (size_t)dir * 8192;

    int g = blockIdx.x * 256 + threadIdx.x;   // 0..131071
    int d = g & (kDI - 1);
    int s = (g >> 9) & 15;
    int b = g >> 13;

    float A2 = -__expf(A_log[d * kDS + s]) * kLOG2E;
    float h = 0.f;
#pragma unroll
    for (int c = 0; c < kNC; ++c) {
        size_t base = ((size_t)(b * kNC + c) * kDS + s) * kDI + d;
        float sv = S[base];
        float sd = sdt[(size_t)(b * kNC + c) * kDI + d];
        S[base] = h;                          // h0 in-place
        h = fmaf(fexp2(sd * A2), h, sv);
    }
}

// ---------------------------------------------------------------------------
// Emit scan: B and C staged to LDS once per block (broadcast reads).
// ---------------------------------------------------------------------------
__global__ __launch_bounds__(256) void scan_emit(
    const unsigned short* __restrict__ dtb2, const unsigned short* __restrict__ xcb2,
    const float* __restrict__ dbl2, const float* __restrict__ A_logb,
    const float* __restrict__ h0v2, const float* __restrict__ Dpb,
    const unsigned short* __restrict__ xz2, unsigned short* __restrict__ yb2)
{
    int dir = blockIdx.y;
    const unsigned short* dtb = dtb2 + (size_t)dir * kM * kDI;
    const unsigned short* xcb = xcb2 + (size_t)dir * kM * kDI;
    const float* dbl = dbl2 + (size_t)dir * kM * 64;
    const float* A_log = A_logb + (size_t)dir * 8192;
    const float* h0v = h0v2 + (size_t)dir * (kB * kNC * kDS * kDI);
    const float* Dp = Dpb + (size_t)dir * 512;
    const unsigned short* zg = xz2 + (size_t)dir * 1024 + 512;
    unsigned short* yb = yb2 + (size_t)dir * kM * kDI;

    int blk  = blockIdx.x;
    int dblk = blk & 1;
    int c    = (blk >> 1) & (kNC - 1);
    int b    = blk >> 6;
    int d    = dblk * 256 + threadIdx.x;

    // stage this chunk's [B|C][32 steps][32] into LDS (each thread: 4 floats)
    __shared__ float bclds[32][32];
    {
        int i = threadIdx.x >> 3, q = (threadIdx.x & 7) * 4;
        int t = dir ? (kL - 1 - (c * kCH + i)) : (c * kCH + i);
        *(float4*)&bclds[i][q] =
            *(const float4*)&dbl[(size_t)(b * kL + t) * 64 + kR + q];
    }
    __syncthreads();

    const float* al = A_log + d * kDS;
    float A2[16];
#pragma unroll
    for (int s = 0; s < 16; ++s) A2[s] = -__expf(al[s]) * kLOG2E;
    float Dd = Dp[d];

    size_t hbase = (size_t)(b * kNC + c) * kDS * kDI + d;
    float h[16];
#pragma unroll
    for (int s = 0; s < 16; ++s) h[s] = h0v[hbase + s * kDI];

#pragma unroll 2
    for (int i = 0; i < kCH; ++i) {
        int p   = c * kCH + i;
        int t   = dir ? (kL - 1 - p) : p;
        int row = b * kL + t;
        float dt = bf2f(dtb[(size_t)row * kDI + d]);
        float xv = bf2f(xcb[(size_t)row * kDI + d]);
        float dx = dt * xv;
        const float4* bp = (const float4*)&bclds[i][0];
        const float4* cp = (const float4*)&bclds[i][16];
        float4 b0 = bp[0], b1 = bp[1], b2 = bp[2], b3 = bp[3];
        float4 c0 = cp[0], c1 = cp[1], c2 = cp[2], c3 = cp[3];
        float Bv[16] = {b0.x, b0.y, b0.z, b0.w, b1.x, b1.y, b1.z, b1.w,
                        b2.x, b2.y, b2.z, b2.w, b3.x, b3.y, b3.z, b3.w};
        float Cv[16] = {c0.x, c0.y, c0.z, c0.w, c1.x, c1.y, c1.z, c1.w,
                        c2.x, c2.y, c2.z, c2.w, c3.x, c3.y, c3.z, c3.w};
        float y = 0.f;
#pragma unroll
        for (int s = 0; s < 16; ++s) {
            float q = fexp2(dt * A2[s]);
            h[s] = fmaf(q, h[s], dx * Bv[s]);
            y = fmaf(h[s], Cv[s], y);
        }
        y += xv * Dd;
        float z = bf2f(zg[(size_t)row * 2048 + d]);
        yb[(size_t)row * kDI + d] = f2bf(y * silu_f(z));
    }
}

// ---------------------------------------------------------------------------
// LayerNorm over rows of 512; optional 2 bf16 add-inputs and bf16 copy.
// ---------------------------------------------------------------------------
__global__ __launch_bounds__(128) void ln_k(
    const float* __restrict__ in, const unsigned short* __restrict__ a0,
    const unsigned short* __restrict__ a1,
    const float* __restrict__ g, const float* __restrict__ bb,
    float* __restrict__ out, unsigned short* __restrict__ outbf)
{
    int row = blockIdx.x;
    int tid = threadIdx.x;
    size_t off = (size_t)row * kDM + tid * 4;
    float4 v = *(const float4*)&in[off];
    if (a0) {
        uint2 u0 = *(const uint2*)&a0[off];
        uint2 u1 = *(const uint2*)&a1[off];
        v.x += bf2f((unsigned short)(u0.x & 0xffff)) + bf2f((unsigned short)(u1.x & 0xffff));
        v.y += bf2f((unsigned short)(u0.x >> 16))    + bf2f((unsigned short)(u1.x >> 16));
        v.z += bf2f((unsigned short)(u0.y & 0xffff)) + bf2f((unsigned short)(u1.y & 0xffff));
        v.w += bf2f((unsigned short)(u0.y >> 16))    + bf2f((unsigned short)(u1.y >> 16));
    }
    float s1 = v.x + v.y + v.z + v.w;
    float s2 = v.x * v.x + v.y * v.y + v.z * v.z + v.w * v.w;
#pragma unroll
    for (int o = 32; o >= 1; o >>= 1) {
        s1 += __shfl_xor(s1, o);
        s2 += __shfl_xor(s2, o);
    }
    __shared__ float red[4];
    if ((tid & 63) == 0) { red[(tid >> 6) * 2] = s1; red[(tid >> 6) * 2 + 1] = s2; }
    __syncthreads();
    s1 = red[0] + red[2];
    s2 = red[1] + red[3];
    float mu  = s1 * (1.f / kDM);
    float var = s2 * (1.f / kDM) - mu * mu;
    float rs  = rsqrtf(var + 1e-5f);
    int cn = tid * 4;
    float4 gv = *(const float4*)&g[cn];
    float4 bv = *(const float4*)&bb[cn];
    float4 o;
    o.x = (v.x - mu) * rs * gv.x + bv.x;
    o.y = (v.y - mu) * rs * gv.y + bv.y;
    o.z = (v.z - mu) * rs * gv.z + bv.z;
    o.w = (v.w - mu) * rs * gv.w + bv.w;
    *(float4*)&out[off] = o;
    if (outbf)
        *(uint2*)&outbf[off] = pack4(o);
}

// ---------------------------------------------------------------------------
extern "C" void kernel_launch(void* const* d_in, const int* in_sizes, int n_in,
                              void* d_out, int out_size, void* d_ws, size_t ws_size,
                              hipStream_t stream)
{
    const float* x_in    = (const float*)d_in[0];
    const float* in_w    = (const float*)d_in[1];
    const float* conv_w  = (const float*)d_in[2];
    const float* conv_b  = (const float*)d_in[3];
    const float* xproj_w = (const float*)d_in[4];
    const float* dt_w    = (const float*)d_in[5];
    const float* dt_b    = (const float*)d_in[6];
    const float* A_log   = (const float*)d_in[7];
    const float* Dp      = (const float*)d_in[8];
    const float* out_w   = (const float*)d_in[9];
    const float* ff_w1   = (const float*)d_in[10];
    const float* ff_b1   = (const float*)d_in[11];
    const float* ff_w2   = (const float*)d_in[12];
    const float* ff_b2   = (const float*)d_in[13];
    const float* ln1_g   = (const float*)d_in[14];
    const float* ln1_b   = (const float*)d_in[15];
    const float* ln2_g   = (const float*)d_in[16];
    const float* ln2_b   = (const float*)d_in[17];
    const float* lnf_g   = (const float*)d_in[18];
    const float* lnf_b   = (const float*)d_in[19];

    float* ws = (float*)d_ws;
    unsigned short* wsb = (unsigned short*)d_ws;

    // bf16 weights (bf16-elem offsets into wsb)
    unsigned short* wb_in  = wsb;                 // in_w   [0, 2097152)
    unsigned short* wb_xp  = wsb + 2097152;       // xproj  [.., 2228224)
    unsigned short* wb_out = wsb + 2228224;       // out_w  [.., 3276800)
    unsigned short* wb_f1  = wsb + 3276800;       // ff_w1  [.., 5373952)
    unsigned short* wb_f2  = wsb + 5373952;       // ff_w2  [.., 7471104)
    unsigned short* wb_dt  = wsb + 7471104;       // dt_w   [.., 7536640)

    constexpr size_t A0 = 3768320;                // f32-word offset of arena
    unsigned short* xbf  = (unsigned short*)(ws + A0);                  // 4.19M w
    unsigned short* xz2  = (unsigned short*)(ws + A0 + 4194304);        // 16.78M w
    unsigned short* xcb2 = (unsigned short*)(ws + A0 + 20971520);       // 8.39M w
    unsigned short* yb2  = (unsigned short*)(ws + A0 + 29360128);       // 8.39M w
    float*          Sb2  = ws + A0 + 37748736;                          // 8.39M w (S/h0)
    unsigned short* dtb2 = (unsigned short*)(ws + A0 + 46137344);       // 8.39M w
    float*          dbl2 = ws + A0 + 54525952;                          // 2.10M w
    unsigned short* dtin2= (unsigned short*)(ws + A0 + 56623104);       // 0.52M w
    float*          sdt2 = ws + A0 + 57147392;                          // 0.52M w
    // out-proj bf16 outputs alias scan scratch (S/h0 dead after scan_emit)
    unsigned short* o2   = (unsigned short*)(ws + A0 + 37748736);       // 8M w as bf16
    // FFN-phase aliases (mamba arena dead)
    float*          xn   = ws + A0;                                     // 8.39M w
    unsigned short* xnbf = (unsigned short*)(ws + A0 + 8388608);        // 4.19M w
    unsigned short* Hb   = (unsigned short*)(ws + A0 + 12582912);       // 16.78M w
    float*          t2   = ws + A0 + 29360128;                          // 8.39M w

    float* xcur = (float*)d_out;
    dim3 thr(256);

    WCvtArgs wa;
    wa.src[0] = in_w;    wa.end[0] = 2097152;
    wa.src[1] = xproj_w; wa.end[1] = 2228224;
    wa.src[2] = out_w;   wa.end[2] = 3276800;
    wa.src[3] = ff_w1;   wa.end[3] = 5373952;
    wa.src[4] = ff_w2;   wa.end[4] = 7471104;
    wa.src[5] = dt_w;    wa.end[5] = 7536640;
    cvt_weights_k<<<dim3(7536640 / 1024), thr, 0, stream>>>(wa, wsb);
    init_x_k<<<dim3(8192), thr, 0, stream>>>(x_in, xcur, xbf);

    for (int e = 0; e < 2; ++e) {
        // in-proj (both dirs fused): (kM x 512) @ (2048 x 512)^T -> xz2 bf16
        gemm_bf16<0, 128, unsigned short><<<dim3(16, 128), thr, 0, stream>>>(
            xbf, 512, 0, wb_in + (size_t)e * 1048576, 0, xz2, 2048, 0,
            nullptr, 0, nullptr, nullptr, 0, 512);
        // conv + silu (both dirs, sliding window)
        conv_silu_k<<<dim3(512), dim3(128), 0, stream>>>(
            xz2, xcb2, conv_w + (size_t)e * 4096, conv_b + (size_t)e * 1024);
        // x-proj (both dirs): -> dbl f32 + dtin bf16
        gemm_bf16<5, 64, float><<<dim3(1, 128, 2), thr, 0, stream>>>(
            xcb2, 512, (size_t)kM * 512, wb_xp + (size_t)e * 65536, 32768,
            dbl2, 64, (size_t)kM * 64, nullptr, 0, nullptr,
            dtin2, (size_t)kM * 32, 512);
        // dt-proj (both dirs): softplus -> dtb2 bf16
        gemm_bf16<1, 128, unsigned short><<<dim3(4, 128, 2), thr, 0, stream>>>(
            dtin2, 32, (size_t)kM * 32, wb_dt + (size_t)e * 32768, 16384,
            dtb2, 512, (size_t)kM * 512, dt_b + (size_t)e * 1024, 512,
            nullptr, nullptr, 0, 32);
        // scans (both dirs)
        scan_chunk<<<dim3(kB * kNC * 2, 2), thr, 0, stream>>>(
            dtb2, xcb2, dbl2, A_log + (size_t)e * 16384, Sb2, sdt2);
        scan_carry<<<dim3(512, 2), thr, 0, stream>>>(
            Sb2, sdt2, A_log + (size_t)e * 16384);
        scan_emit<<<dim3(kB * kNC * 2, 2), thr, 0, stream>>>(
            dtb2, xcb2, dbl2, A_log + (size_t)e * 16384, Sb2,
            Dp + (size_t)e * 1024, xz2, yb2);
        // out-proj (both dirs) -> o2 bf16 (separate buffers; LN1 adds)
        gemm_bf16<0, 128, unsigned short><<<dim3(4, 128, 2), thr, 0, stream>>>(
            yb2, 512, (size_t)kM * 512, wb_out + (size_t)e * 524288, 262144,
            o2, 512, (size_t)kM * 512, nullptr, 0, nullptr, nullptr, 0, 512);
        // LN1: normalize (xcur + o0 + o1) -> xn f32 + xnbf bf16
        ln_k<<<dim3(kM), dim3(128), 0, stream>>>(
            xcur, o2, o2 + (size_t)kM * 512,
            ln1_g + e * kDM, ln1_b + e * kDM, xn, xnbf);
        // FFN1: gelu(xn @ w1^T + b1) -> Hb bf16
        gemm_bf16<3, 128, unsigned short><<<dim3(16, 128), thr, 0, stream>>>(
            xnbf, 512, 0, wb_f1 + (size_t)e * 1048576, 0, Hb, 2048, 0,
            ff_b1 + (size_t)e * kDFF, 0, nullptr, nullptr, 0, 512);
        // FFN2: Hb @ w2^T + b2 + xn -> t2 f32
        gemm_bf16<4, 128, float><<<dim3(4, 128), thr, 0, stream>>>(
            Hb, 2048, 0, wb_f2 + (size_t)e * 1048576, 0, t2, 512, 0,
            ff_b2 + (size_t)e * kDM, 0, xn, nullptr, 0, 2048);
        // LN2 -> xcur (+ bf16 snapshot for next layer)
        ln_k<<<dim3(kM), dim3(128), 0, stream>>>(
            t2, nullptr, nullptr, ln2_g + e * kDM, ln2_b + e * kDM, xcur,
            e == 0 ? xbf : nullptr);
    }
    ln_k<<<dim3(kM), dim3(128), 0, stream>>>(
        xcur, nullptr, nullptr, lnf_g, lnf_b, xcur, nullptr);
}

// Round 15
// 880.074 us; speedup vs baseline: 1.0723x; 1.0688x over previous
//
#include <hip/hip_runtime.h>
#include <hip/hip_bf16.h>
#include <math.h>

#define DEVI __device__ __forceinline__

namespace {
constexpr int kL   = 1024;
constexpr int kDM  = 512;
constexpr int kDS  = 16;
constexpr int kDFF = 2048;
constexpr int kR   = 32;
constexpr int kDI  = 512;
constexpr int kB   = 16;
constexpr int kM   = kB * kL;     // 16384 rows
constexpr int kNC  = 32;          // scan chunks
constexpr int kCH  = kL / kNC;    // 32 steps per chunk
constexpr float kLOG2E = 1.4426950408889634f;
}

typedef __attribute__((ext_vector_type(8))) short short8;
typedef __attribute__((ext_vector_type(4))) float f32x4;

DEVI float silu_f(float x)     { return x / (1.f + __expf(-x)); }
DEVI float softplus_f(float x) { return fmaxf(x, 0.f) + log1pf(__expf(-fabsf(x))); }
DEVI float gelu_f(float x)     { return 0.5f * x * (1.f + erff(x * 0.70710678118654752f)); }

// raw hardware exp2 (v_exp_f32): 1 instruction, no libm wrapper
DEVI float fexp2(float x) {
    float r;
    asm("v_exp_f32 %0, %1" : "=v"(r) : "v"(x));
    return r;
}

DEVI unsigned short f2bf(float f) {
    unsigned int u = __float_as_uint(f);
    return (unsigned short)((u + 0x7fffu + ((u >> 16) & 1u)) >> 16);
}
DEVI float bf2f(unsigned short u) {
    return __uint_as_float(((unsigned int)u) << 16);
}
DEVI uint2 pack4(float4 v) {
    uint2 p;
    p.x = (unsigned int)f2bf(v.x) | ((unsigned int)f2bf(v.y) << 16);
    p.y = (unsigned int)f2bf(v.z) | ((unsigned int)f2bf(v.w) << 16);
    return p;
}

// log-depth power tree: qq[s] = r^(s+1), 15 muls, dependency depth 4
DEVI void powtree16(float r, float* qq) {
    qq[0] = r;
#pragma unroll
    for (int s = 1; s < 16; ++s) {
        int a = (s - 1) >> 1, b = (s - 1) - a;
        qq[s] = qq[a] * qq[b];
    }
}

typedef const __attribute__((address_space(1))) unsigned int* gas1;
typedef __attribute__((address_space(3))) unsigned int* las3;
DEVI void gload16(const unsigned short* g, unsigned short* l) {
    __builtin_amdgcn_global_load_lds((gas1)g, (las3)l, 16, 0, 0);
}

// ---------------------------------------------------------------------------
// One-shot weight conversion f32 -> bf16 (6 segments).
// ---------------------------------------------------------------------------
struct WCvtArgs { const float* src[6]; unsigned int end[6]; };

__global__ __launch_bounds__(256) void cvt_weights_k(
    WCvtArgs a, unsigned short* __restrict__ dst)
{
    unsigned int i = (blockIdx.x * 256 + threadIdx.x) * 4;
    if (i >= a.end[5]) return;
    int j = 0;
    while (i >= a.end[j]) ++j;
    unsigned int base = j ? a.end[j - 1] : 0;
    float4 v = *(const float4*)&a.src[j][i - base];
    *(uint2*)&dst[i] = pack4(v);
}

__global__ __launch_bounds__(256) void init_x_k(
    const float* __restrict__ x, float* __restrict__ xo,
    unsigned short* __restrict__ xb)
{
    size_t i = (size_t)(blockIdx.x * 256 + threadIdx.x) * 4;
    float4 v = *(const float4*)&x[i];
    *(float4*)&xo[i] = v;
    *(uint2*)&xb[i] = pack4(v);
}

// ---------------------------------------------------------------------------
// bf16 MFMA GEMM: 128 x BN, BK=32, 4 waves, double-buffered LDS with
// counted-vmcnt pipeline. EPI: 0 plain (CT), 1 bias+softplus (CT),
// 3 bias+gelu (bf16), 4 bias+add (f32), 5 f32 + bf16 aux cols<32. z-batched.
// ---------------------------------------------------------------------------
template <int EPI, int BN, typename CT>
__global__ __launch_bounds__(256) void gemm_bf16(
    const unsigned short* __restrict__ A, int lda, size_t zA,
    const unsigned short* __restrict__ W, size_t zW,
    CT* __restrict__ C, int ldc, size_t zC,
    const float* __restrict__ biasb, int zBias,
    const float* __restrict__ add,
    unsigned short* __restrict__ auxb, size_t zAux, int Kd)
{
    static_assert(BN == 64 || BN == 128, "");
    constexpr int NF = BN / 32;
    __shared__ alignas(16) unsigned short As[2][128 * 32];
    __shared__ alignas(16) unsigned short Ws[2][BN * 32];

    const int z = blockIdx.z;
    A += (size_t)z * zA; W += (size_t)z * zW; C += (size_t)z * zC;
    const float* bias = biasb ? biasb + (size_t)z * zBias : nullptr;
    unsigned short* aux = auxb ? auxb + (size_t)z * zAux : nullptr;

    const int gx = gridDim.x;
    int flat = blockIdx.y * gx + blockIdx.x;
    const int total = gx * gridDim.y;
    if ((total & 7) == 0) {
        int q = total >> 3;
        flat = (flat & 7) * q + (flat >> 3);
    }
    const int bx = flat % gx;
    const int by = flat / gx;

    const int tid  = threadIdx.x;
    const int lane = tid & 63;
    const int wv   = tid >> 6;
    const int wm   = wv >> 1;
    const int wn   = wv & 1;
    const int row0 = by * 128;
    const int col0 = bx * BN;

    f32x4 acc[4][NF];
#pragma unroll
    for (int m = 0; m < 4; ++m)
#pragma unroll
        for (int n = 0; n < NF; ++n) acc[m][n] = (f32x4){0.f, 0.f, 0.f, 0.f};

    const int sr  = tid >> 2;
    const int scw = (((tid & 3) ^ ((tid >> 3) & 3)) * 8);
    const unsigned short* Ag = A + (size_t)(row0 + sr) * lda + scw;
    const unsigned short* Wg = W + (size_t)(col0 + sr) * Kd + scw;

    auto stage = [&](int buf, int k0) {
        gload16(Ag + k0, &As[buf][tid * 8]);
        gload16(Ag + (size_t)64 * lda + k0, &As[buf][2048 + tid * 8]);
        gload16(Wg + k0, &Ws[buf][tid * 8]);
        if (BN == 128)
            gload16(Wg + (size_t)64 * Kd + k0, &Ws[buf][2048 + tid * 8]);
    };

    const int nt = Kd / 32;
    stage(0, 0);
    if (nt > 1) stage(1, 32);

    const int fr  = lane & 15;
    const int sw8 = (((lane >> 4) ^ ((fr >> 1) & 3)) * 8);

    for (int t = 0; t < nt; ++t) {
        const int cur = t & 1;
        if (t + 1 < nt) {
            if constexpr (BN == 128) asm volatile("s_waitcnt vmcnt(4)" ::: "memory");
            else                     asm volatile("s_waitcnt vmcnt(3)" ::: "memory");
        } else {
            asm volatile("s_waitcnt vmcnt(0)" ::: "memory");
        }
        __builtin_amdgcn_sched_barrier(0);
        __builtin_amdgcn_s_barrier();
        __builtin_amdgcn_sched_barrier(0);

        short8 af[4], bf[NF];
#pragma unroll
        for (int m = 0; m < 4; ++m)
            af[m] = *(const short8*)&As[cur][(wm * 64 + m * 16 + fr) * 32 + sw8];
#pragma unroll
        for (int n = 0; n < NF; ++n)
            bf[n] = *(const short8*)&Ws[cur][(wn * (BN / 2) + n * 16 + fr) * 32 + sw8];
        __builtin_amdgcn_s_setprio(1);
#pragma unroll
        for (int m = 0; m < 4; ++m)
#pragma unroll
            for (int n = 0; n < NF; ++n)
                acc[m][n] = __builtin_amdgcn_mfma_f32_16x16x32_bf16(
                    af[m], bf[n], acc[m][n], 0, 0, 0);
        __builtin_amdgcn_s_setprio(0);

        __builtin_amdgcn_sched_barrier(0);
        __builtin_amdgcn_s_barrier();
        __builtin_amdgcn_sched_barrier(0);
        if (t + 2 < nt) stage(cur, (t + 2) * 32);
    }

    const int cr = (lane >> 4) * 4;
#pragma unroll
    for (int m = 0; m < 4; ++m) {
#pragma unroll
        for (int n = 0; n < NF; ++n) {
            int cn = col0 + wn * (BN / 2) + n * 16 + fr;
#pragma unroll
            for (int r = 0; r < 4; ++r) {
                int rr = row0 + wm * 64 + m * 16 + cr + r;
                size_t idx = (size_t)rr * ldc + cn;
                float v = acc[m][n][r];
                if constexpr (EPI == 0) {
                    if constexpr (__is_same(CT, unsigned short)) C[idx] = f2bf(v);
                    else C[idx] = v;
                } else if constexpr (EPI == 1) {
                    float sp = softplus_f(v + bias[cn]);
                    if constexpr (__is_same(CT, unsigned short)) C[idx] = f2bf(sp);
                    else C[idx] = sp;
                } else if constexpr (EPI == 3) {
                    C[idx] = f2bf(gelu_f(v + bias[cn]));
                } else if constexpr (EPI == 4) {
                    C[idx] = v + bias[cn] + add[idx];
                } else {  // 5: f32 out + bf16 aux for cols < 32
                    C[idx] = v;
                    if (cn < 32) aux[(size_t)rr * 32 + cn] = f2bf(v);
                }
            }
        }
    }
}

// ---------------------------------------------------------------------------
// Sliding-window depthwise conv (K=4) + bias + silu.
// ---------------------------------------------------------------------------
__global__ __launch_bounds__(128) void conv_silu_k(
    const unsigned short* __restrict__ xz2, unsigned short* __restrict__ xcb,
    const float* __restrict__ wb, const float* __restrict__ biasb)
{
    const int task = blockIdx.x * 128 + threadIdx.x;
    const int g   = task & 63;
    const int c   = (task >> 6) & 31;
    const int b   = (task >> 11) & 15;
    const int dir = (task >> 15) & 1;
    const int d0  = g * 8;

    const unsigned short* xzd = xz2 + (size_t)dir * 1024 + (size_t)b * kL * 2048 + d0;
    unsigned short* xc = xcb + (size_t)dir * kM * kDI + (size_t)b * kL * kDI + d0;
    const float* w    = wb + (size_t)dir * 2048;
    const float* bias = biasb + (size_t)dir * 512;

    float wk[4][8];
#pragma unroll
    for (int k = 0; k < 4; ++k)
#pragma unroll
        for (int j = 0; j < 8; ++j)
            wk[k][j] = w[(d0 + j) * 4 + (dir ? 3 - k : k)];
    float bs[8];
#pragma unroll
    for (int j = 0; j < 8; ++j) bs[j] = bias[d0 + j];

    const int t0 = c * 32;
    const int rbase = dir ? t0 : t0 - 3;

    auto loadrow = [&](int t, float* o) {
        if (t < 0 || t >= kL) {
#pragma unroll
            for (int j = 0; j < 8; ++j) o[j] = 0.f;
            return;
        }
        uint4 p = *(const uint4*)&xzd[(size_t)t * 2048];
        o[0] = bf2f((unsigned short)(p.x & 0xffff));
        o[1] = bf2f((unsigned short)(p.x >> 16));
        o[2] = bf2f((unsigned short)(p.y & 0xffff));
        o[3] = bf2f((unsigned short)(p.y >> 16));
        o[4] = bf2f((unsigned short)(p.z & 0xffff));
        o[5] = bf2f((unsigned short)(p.z >> 16));
        o[6] = bf2f((unsigned short)(p.w & 0xffff));
        o[7] = bf2f((unsigned short)(p.w >> 16));
    };

    float x0[8], x1[8], x2[8];
    loadrow(rbase + 0, x0);
    loadrow(rbase + 1, x1);
    loadrow(rbase + 2, x2);

#pragma unroll 4
    for (int i = 0; i < 32; ++i) {
        float x3[8];
        loadrow(rbase + 3 + i, x3);
        unsigned short o[8];
#pragma unroll
        for (int j = 0; j < 8; ++j) {
            float v = bs[j];
            v = fmaf(wk[0][j], x0[j], v);
            v = fmaf(wk[1][j], x1[j], v);
            v = fmaf(wk[2][j], x2[j], v);
            v = fmaf(wk[3][j], x3[j], v);
            o[j] = f2bf(silu_f(v));
        }
        *(uint4*)&xc[(size_t)(t0 + i) * kDI] = *(uint4*)o;
#pragma unroll
        for (int j = 0; j < 8; ++j) { x0[j] = x1[j]; x1[j] = x2[j]; x2[j] = x3[j]; }
    }
}

// ---------------------------------------------------------------------------
// Chunked selective scan, both dirs (blockIdx.y = dir). dt bf16. B staged to
// LDS once per block. Fast path: A_log rows form exact geometric family
// A2[s] = (s+1)*A2[0] (true for this model's A_log = log(arange(1,17))) ->
// one v_exp + 15 muls (power tree) replaces 16 trans ops per step. Guarded
// by a runtime check; falls back to exact 16-exp loop otherwise.
// ---------------------------------------------------------------------------
__global__ __launch_bounds__(256) void scan_chunk(
    const unsigned short* __restrict__ dtb2, const unsigned short* __restrict__ xcb2,
    const float* __restrict__ dbl2, const float* __restrict__ A_logb,
    float* __restrict__ S2, float* __restrict__ sdt2)
{
    int dir = blockIdx.y;
    const unsigned short* dtb = dtb2 + (size_t)dir * kM * kDI;
    const unsigned short* xcb = xcb2 + (size_t)dir * kM * kDI;
    const float* dbl = dbl2 + (size_t)dir * kM * 64;
    const float* A_log = A_logb + (size_t)dir * 8192;
    float* S   = S2 + (size_t)dir * (kB * kNC * kDS * kDI);
    float* sdt = sdt2 + (size_t)dir * (kB * kNC * kDI);

    int blk  = blockIdx.x;
    int dblk = blk & 1;
    int c    = (blk >> 1) & (kNC - 1);
    int b    = blk >> 6;
    int d    = dblk * 256 + threadIdx.x;

    __shared__ float blds[32][16];
    {
        int i = threadIdx.x >> 3, q = (threadIdx.x & 7) * 2;
        int t = dir ? (kL - 1 - (c * kCH + i)) : (c * kCH + i);
        *(float2*)&blds[i][q] =
            *(const float2*)&dbl[(size_t)(b * kL + t) * 64 + kR + q];
    }
    __syncthreads();

    const float* al = A_log + d * kDS;
    float A2[16];
#pragma unroll
    for (int s = 0; s < 16; ++s) A2[s] = -__expf(al[s]) * kLOG2E;

    bool fast = true;
#pragma unroll
    for (int s = 1; s < 16; ++s)
        fast = fast && (fabsf(A2[s] - A2[0] * (float)(s + 1)) <= 1e-4f * fabsf(A2[s]));

    float h[16];
#pragma unroll
    for (int s = 0; s < 16; ++s) h[s] = 0.f;
    float sum = 0.f;

    if (fast) {
        const float A0 = A2[0];
#pragma unroll 2
        for (int i = 0; i < kCH; ++i) {
            int p   = c * kCH + i;
            int t   = dir ? (kL - 1 - p) : p;
            int row = b * kL + t;
            float dt = bf2f(dtb[(size_t)row * kDI + d]);
            float xv = bf2f(xcb[(size_t)row * kDI + d]);
            sum += dt;
            float dx = dt * xv;
            float qq[16];
            powtree16(fexp2(dt * A0), qq);
            const float4* bp = (const float4*)&blds[i][0];
            float4 b0 = bp[0], b1 = bp[1], b2 = bp[2], b3 = bp[3];
            float Bv[16] = {b0.x, b0.y, b0.z, b0.w, b1.x, b1.y, b1.z, b1.w,
                            b2.x, b2.y, b2.z, b2.w, b3.x, b3.y, b3.z, b3.w};
#pragma unroll
            for (int s = 0; s < 16; ++s)
                h[s] = fmaf(qq[s], h[s], dx * Bv[s]);
        }
    } else {
#pragma unroll 2
        for (int i = 0; i < kCH; ++i) {
            int p   = c * kCH + i;
            int t   = dir ? (kL - 1 - p) : p;
            int row = b * kL + t;
            float dt = bf2f(dtb[(size_t)row * kDI + d]);
            float xv = bf2f(xcb[(size_t)row * kDI + d]);
            sum += dt;
            float dx = dt * xv;
            const float4* bp = (const float4*)&blds[i][0];
            float4 b0 = bp[0], b1 = bp[1], b2 = bp[2], b3 = bp[3];
            float Bv[16] = {b0.x, b0.y, b0.z, b0.w, b1.x, b1.y, b1.z, b1.w,
                            b2.x, b2.y, b2.z, b2.w, b3.x, b3.y, b3.z, b3.w};
#pragma unroll
            for (int s = 0; s < 16; ++s) {
                float q = fexp2(dt * A2[s]);
                h[s] = fmaf(q, h[s], dx * Bv[s]);
            }
        }
    }
    size_t base = (size_t)(b * kNC + c) * kDS * kDI + d;
#pragma unroll
    for (int s = 0; s < 16; ++s) S[base + s * kDI] = h[s];
    sdt[(size_t)(b * kNC + c) * kDI + d] = sum;
}

// ---------------------------------------------------------------------------
// Carry scan: one thread per (b,d,s) recurrence; h0 written in-place over S.
// ---------------------------------------------------------------------------
__global__ __launch_bounds__(256) void scan_carry(
    float* __restrict__ S2, const float* __restrict__ sdt2,
    const float* __restrict__ A_logb)
{
    int dir = blockIdx.y;
    float* S = S2 + (size_t)dir * (kB * kNC * kDS * kDI);
    const float* sdt = sdt2 + (size_t)dir * (kB * kNC * kDI);
    const float* A_log = A_logb + (size_t)dir * 8192;

    int g = blockIdx.x * 256 + threadIdx.x;   // 0..131071
    int d = g & (kDI - 1);
    int s = (g >> 9) & 15;
    int b = g >> 13;

    float A2 = -__expf(A_log[d * kDS + s]) * kLOG2E;
    float h = 0.f;
#pragma unroll
    for (int c = 0; c < kNC; ++c) {
        size_t base = ((size_t)(b * kNC + c) * kDS + s) * kDI + d;
        float sv = S[base];
        float sd = sdt[(size_t)(b * kNC + c) * kDI + d];
        S[base] = h;                          // h0 in-place
        h = fmaf(fexp2(sd * A2), h, sv);
    }
}

// ---------------------------------------------------------------------------
// Emit scan: B/C staged to LDS; same guarded geometric fast path.
// ---------------------------------------------------------------------------
__global__ __launch_bounds__(256) void scan_emit(
    const unsigned short* __restrict__ dtb2, const unsigned short* __restrict__ xcb2,
    const float* __restrict__ dbl2, const float* __restrict__ A_logb,
    const float* __restrict__ h0v2, const float* __restrict__ Dpb,
    const unsigned short* __restrict__ xz2, unsigned short* __restrict__ yb2)
{
    int dir = blockIdx.y;
    const unsigned short* dtb = dtb2 + (size_t)dir * kM * kDI;
    const unsigned short* xcb = xcb2 + (size_t)dir * kM * kDI;
    const float* dbl = dbl2 + (size_t)dir * kM * 64;
    const float* A_log = A_logb + (size_t)dir * 8192;
    const float* h0v = h0v2 + (size_t)dir * (kB * kNC * kDS * kDI);
    const float* Dp = Dpb + (size_t)dir * 512;
    const unsigned short* zg = xz2 + (size_t)dir * 1024 + 512;
    unsigned short* yb = yb2 + (size_t)dir * kM * kDI;

    int blk  = blockIdx.x;
    int dblk = blk & 1;
    int c    = (blk >> 1) & (kNC - 1);
    int b    = blk >> 6;
    int d    = dblk * 256 + threadIdx.x;

    __shared__ float bclds[32][32];
    {
        int i = threadIdx.x >> 3, q = (threadIdx.x & 7) * 4;
        int t = dir ? (kL - 1 - (c * kCH + i)) : (c * kCH + i);
        *(float4*)&bclds[i][q] =
            *(const float4*)&dbl[(size_t)(b * kL + t) * 64 + kR + q];
    }
    __syncthreads();

    const float* al = A_log + d * kDS;
    float A2[16];
#pragma unroll
    for (int s = 0; s < 16; ++s) A2[s] = -__expf(al[s]) * kLOG2E;
    float Dd = Dp[d];

    bool fast = true;
#pragma unroll
    for (int s = 1; s < 16; ++s)
        fast = fast && (fabsf(A2[s] - A2[0] * (float)(s + 1)) <= 1e-4f * fabsf(A2[s]));

    size_t hbase = (size_t)(b * kNC + c) * kDS * kDI + d;
    float h[16];
#pragma unroll
    for (int s = 0; s < 16; ++s) h[s] = h0v[hbase + s * kDI];

    if (fast) {
        const float A0 = A2[0];
#pragma unroll 2
        for (int i = 0; i < kCH; ++i) {
            int p   = c * kCH + i;
            int t   = dir ? (kL - 1 - p) : p;
            int row = b * kL + t;
            float dt = bf2f(dtb[(size_t)row * kDI + d]);
            float xv = bf2f(xcb[(size_t)row * kDI + d]);
            float dx = dt * xv;
            float qq[16];
            powtree16(fexp2(dt * A0), qq);
            const float4* bp = (const float4*)&bclds[i][0];
            const float4* cp = (const float4*)&bclds[i][16];
            float4 b0 = bp[0], b1 = bp[1], b2 = bp[2], b3 = bp[3];
            float4 c0 = cp[0], c1 = cp[1], c2 = cp[2], c3 = cp[3];
            float Bv[16] = {b0.x, b0.y, b0.z, b0.w, b1.x, b1.y, b1.z, b1.w,
                            b2.x, b2.y, b2.z, b2.w, b3.x, b3.y, b3.z, b3.w};
            float Cv[16] = {c0.x, c0.y, c0.z, c0.w, c1.x, c1.y, c1.z, c1.w,
                            c2.x, c2.y, c2.z, c2.w, c3.x, c3.y, c3.z, c3.w};
            float y = 0.f;
#pragma unroll
            for (int s = 0; s < 16; ++s) {
                h[s] = fmaf(qq[s], h[s], dx * Bv[s]);
                y = fmaf(h[s], Cv[s], y);
            }
            y += xv * Dd;
            float zv = bf2f(zg[(size_t)row * 2048 + d]);
            yb[(size_t)row * kDI + d] = f2bf(y * silu_f(zv));
        }
    } else {
#pragma unroll 2
        for (int i = 0; i < kCH; ++i) {
            int p   = c * kCH + i;
            int t   = dir ? (kL - 1 - p) : p;
            int row = b * kL + t;
            float dt = bf2f(dtb[(size_t)row * kDI + d]);
            float xv = bf2f(xcb[(size_t)row * kDI + d]);
            float dx = dt * xv;
            const float4* bp = (const float4*)&bclds[i][0];
            const float4* cp = (const float4*)&bclds[i][16];
            float4 b0 = bp[0], b1 = bp[1], b2 = bp[2], b3 = bp[3];
            float4 c0 = cp[0], c1 = cp[1], c2 = cp[2], c3 = cp[3];
            float Bv[16] = {b0.x, b0.y, b0.z, b0.w, b1.x, b1.y, b1.z, b1.w,
                            b2.x, b2.y, b2.z, b2.w, b3.x, b3.y, b3.z, b3.w};
            float Cv[16] = {c0.x, c0.y, c0.z, c0.w, c1.x, c1.y, c1.z, c1.w,
                            c2.x, c2.y, c2.z, c2.w, c3.x, c3.y, c3.z, c3.w};
            float y = 0.f;
#pragma unroll
            for (int s = 0; s < 16; ++s) {
                float q = fexp2(dt * A2[s]);
                h[s] = fmaf(q, h[s], dx * Bv[s]);
                y = fmaf(h[s], Cv[s], y);
            }
            y += xv * Dd;
            float zv = bf2f(zg[(size_t)row * 2048 + d]);
            yb[(size_t)row * kDI + d] = f2bf(y * silu_f(zv));
        }
    }
}

// ---------------------------------------------------------------------------
// LayerNorm over rows of 512; optional 2 bf16 add-inputs and bf16 copy.
// ---------------------------------------------------------------------------
__global__ __launch_bounds__(128) void ln_k(
    const float* __restrict__ in, const unsigned short* __restrict__ a0,
    const unsigned short* __restrict__ a1,
    const float* __restrict__ g, const float* __restrict__ bb,
    float* __restrict__ out, unsigned short* __restrict__ outbf)
{
    int row = blockIdx.x;
    int tid = threadIdx.x;
    size_t off = (size_t)row * kDM + tid * 4;
    float4 v = *(const float4*)&in[off];
    if (a0) {
        uint2 u0 = *(const uint2*)&a0[off];
        uint2 u1 = *(const uint2*)&a1[off];
        v.x += bf2f((unsigned short)(u0.x & 0xffff)) + bf2f((unsigned short)(u1.x & 0xffff));
        v.y += bf2f((unsigned short)(u0.x >> 16))    + bf2f((unsigned short)(u1.x >> 16));
        v.z += bf2f((unsigned short)(u0.y & 0xffff)) + bf2f((unsigned short)(u1.y & 0xffff));
        v.w += bf2f((unsigned short)(u0.y >> 16))    + bf2f((unsigned short)(u1.y >> 16));
    }
    float s1 = v.x + v.y + v.z + v.w;
    float s2 = v.x * v.x + v.y * v.y + v.z * v.z + v.w * v.w;
#pragma unroll
    for (int o = 32; o >= 1; o >>= 1) {
        s1 += __shfl_xor(s1, o);
        s2 += __shfl_xor(s2, o);
    }
    __shared__ float red[4];
    if ((tid & 63) == 0) { red[(tid >> 6) * 2] = s1; red[(tid >> 6) * 2 + 1] = s2; }
    __syncthreads();
    s1 = red[0] + red[2];
    s2 = red[1] + red[3];
    float mu  = s1 * (1.f / kDM);
    float var = s2 * (1.f / kDM) - mu * mu;
    float rs  = rsqrtf(var + 1e-5f);
    int cn = tid * 4;
    float4 gv = *(const float4*)&g[cn];
    float4 bv = *(const float4*)&bb[cn];
    float4 o;
    o.x = (v.x - mu) * rs * gv.x + bv.x;
    o.y = (v.y - mu) * rs * gv.y + bv.y;
    o.z = (v.z - mu) * rs * gv.z + bv.z;
    o.w = (v.w - mu) * rs * gv.w + bv.w;
    *(float4*)&out[off] = o;
    if (outbf)
        *(uint2*)&outbf[off] = pack4(o);
}

// ---------------------------------------------------------------------------
extern "C" void kernel_launch(void* const* d_in, const int* in_sizes, int n_in,
                              void* d_out, int out_size, void* d_ws, size_t ws_size,
                              hipStream_t stream)
{
    const float* x_in    = (const float*)d_in[0];
    const float* in_w    = (const float*)d_in[1];
    const float* conv_w  = (const float*)d_in[2];
    const float* conv_b  = (const float*)d_in[3];
    const float* xproj_w = (const float*)d_in[4];
    const float* dt_w    = (const float*)d_in[5];
    const float* dt_b    = (const float*)d_in[6];
    const float* A_log   = (const float*)d_in[7];
    const float* Dp      = (const float*)d_in[8];
    const float* out_w   = (const float*)d_in[9];
    const float* ff_w1   = (const float*)d_in[10];
    const float* ff_b1   = (const float*)d_in[11];
    const float* ff_w2   = (const float*)d_in[12];
    const float* ff_b2   = (const float*)d_in[13];
    const float* ln1_g   = (const float*)d_in[14];
    const float* ln1_b   = (const float*)d_in[15];
    const float* ln2_g   = (const float*)d_in[16];
    const float* ln2_b   = (const float*)d_in[17];
    const float* lnf_g   = (const float*)d_in[18];
    const float* lnf_b   = (const float*)d_in[19];

    float* ws = (float*)d_ws;
    unsigned short* wsb = (unsigned short*)d_ws;

    // bf16 weights (bf16-elem offsets into wsb)
    unsigned short* wb_in  = wsb;                 // in_w   [0, 2097152)
    unsigned short* wb_xp  = wsb + 2097152;       // xproj  [.., 2228224)
    unsigned short* wb_out = wsb + 2228224;       // out_w  [.., 3276800)
    unsigned short* wb_f1  = wsb + 3276800;       // ff_w1  [.., 5373952)
    unsigned short* wb_f2  = wsb + 5373952;       // ff_w2  [.., 7471104)
    unsigned short* wb_dt  = wsb + 7471104;       // dt_w   [.., 7536640)

    constexpr size_t A0 = 3768320;                // f32-word offset of arena
    unsigned short* xbf  = (unsigned short*)(ws + A0);                  // 4.19M w
    unsigned short* xz2  = (unsigned short*)(ws + A0 + 4194304);        // 16.78M w
    unsigned short* xcb2 = (unsigned short*)(ws + A0 + 20971520);       // 8.39M w
    unsigned short* yb2  = (unsigned short*)(ws + A0 + 29360128);       // 8.39M w
    float*          Sb2  = ws + A0 + 37748736;                          // 8.39M w (S/h0)
    unsigned short* dtb2 = (unsigned short*)(ws + A0 + 46137344);       // 8.39M w
    float*          dbl2 = ws + A0 + 54525952;                          // 2.10M w
    unsigned short* dtin2= (unsigned short*)(ws + A0 + 56623104);       // 0.52M w
    float*          sdt2 = ws + A0 + 57147392;                          // 0.52M w
    // out-proj bf16 outputs alias scan scratch (S/h0 dead after scan_emit)
    unsigned short* o2   = (unsigned short*)(ws + A0 + 37748736);       // 8M w as bf16
    // FFN-phase aliases (mamba arena dead)
    float*          xn   = ws + A0;                                     // 8.39M w
    unsigned short* xnbf = (unsigned short*)(ws + A0 + 8388608);        // 4.19M w
    unsigned short* Hb   = (unsigned short*)(ws + A0 + 12582912);       // 16.78M w
    float*          t2   = ws + A0 + 29360128;                          // 8.39M w

    float* xcur = (float*)d_out;
    dim3 thr(256);

    WCvtArgs wa;
    wa.src[0] = in_w;    wa.end[0] = 2097152;
    wa.src[1] = xproj_w; wa.end[1] = 2228224;
    wa.src[2] = out_w;   wa.end[2] = 3276800;
    wa.src[3] = ff_w1;   wa.end[3] = 5373952;
    wa.src[4] = ff_w2;   wa.end[4] = 7471104;
    wa.src[5] = dt_w;    wa.end[5] = 7536640;
    cvt_weights_k<<<dim3(7536640 / 1024), thr, 0, stream>>>(wa, wsb);
    init_x_k<<<dim3(8192), thr, 0, stream>>>(x_in, xcur, xbf);

    for (int e = 0; e < 2; ++e) {
        // in-proj (both dirs fused): (kM x 512) @ (2048 x 512)^T -> xz2 bf16
        gemm_bf16<0, 128, unsigned short><<<dim3(16, 128), thr, 0, stream>>>(
            xbf, 512, 0, wb_in + (size_t)e * 1048576, 0, xz2, 2048, 0,
            nullptr, 0, nullptr, nullptr, 0, 512);
        // conv + silu (both dirs, sliding window)
        conv_silu_k<<<dim3(512), dim3(128), 0, stream>>>(
            xz2, xcb2, conv_w + (size_t)e * 4096, conv_b + (size_t)e * 1024);
        // x-proj (both dirs): -> dbl f32 + dtin bf16
        gemm_bf16<5, 64, float><<<dim3(1, 128, 2), thr, 0, stream>>>(
            xcb2, 512, (size_t)kM * 512, wb_xp + (size_t)e * 65536, 32768,
            dbl2, 64, (size_t)kM * 64, nullptr, 0, nullptr,
            dtin2, (size_t)kM * 32, 512);
        // dt-proj (both dirs): softplus -> dtb2 bf16
        gemm_bf16<1, 128, unsigned short><<<dim3(4, 128, 2), thr, 0, stream>>>(
            dtin2, 32, (size_t)kM * 32, wb_dt + (size_t)e * 32768, 16384,
            dtb2, 512, (size_t)kM * 512, dt_b + (size_t)e * 1024, 512,
            nullptr, nullptr, 0, 32);
        // scans (both dirs)
        scan_chunk<<<dim3(kB * kNC * 2, 2), thr, 0, stream>>>(
            dtb2, xcb2, dbl2, A_log + (size_t)e * 16384, Sb2, sdt2);
        scan_carry<<<dim3(512, 2), thr, 0, stream>>>(
            Sb2, sdt2, A_log + (size_t)e * 16384);
        scan_emit<<<dim3(kB * kNC * 2, 2), thr, 0, stream>>>(
            dtb2, xcb2, dbl2, A_log + (size_t)e * 16384, Sb2,
            Dp + (size_t)e * 1024, xz2, yb2);
        // out-proj (both dirs) -> o2 bf16 (separate buffers; LN1 adds)
        gemm_bf16<0, 128, unsigned short><<<dim3(4, 128, 2), thr, 0, stream>>>(
            yb2, 512, (size_t)kM * 512, wb_out + (size_t)e * 524288, 262144,
            o2, 512, (size_t)kM * 512, nullptr, 0, nullptr, nullptr, 0, 512);
        // LN1: normalize (xcur + o0 + o1) -> xn f32 + xnbf bf16
        ln_k<<<dim3(kM), dim3(128), 0, stream>>>(
            xcur, o2, o2 + (size_t)kM * 512,
            ln1_g + e * kDM, ln1_b + e * kDM, xn, xnbf);
        // FFN1: gelu(xn @ w1^T + b1) -> Hb bf16
        gemm_bf16<3, 128, unsigned short><<<dim3(16, 128), thr, 0, stream>>>(
            xnbf, 512, 0, wb_f1 + (size_t)e * 1048576, 0, Hb, 2048, 0,
            ff_b1 + (size_t)e * kDFF, 0, nullptr, nullptr, 0, 512);
        // FFN2: Hb @ w2^T + b2 + xn -> t2 f32
        gemm_bf16<4, 128, float><<<dim3(4, 128), thr, 0, stream>>>(
            Hb, 2048, 0, wb_f2 + (size_t)e * 1048576, 0, t2, 512, 0,
            ff_b2 + (size_t)e * kDM, 0, xn, nullptr, 0, 2048);
        // LN2 -> xcur (+ bf16 snapshot for next layer)
        ln_k<<<dim3(kM), dim3(128), 0, stream>>>(
            t2, nullptr, nullptr, ln2_g + e * kDM, ln2_b + e * kDM, xcur,
            e == 0 ? xbf : nullptr);
    }
    ln_k<<<dim3(kM), dim3(128), 0, stream>>>(
        xcur, nullptr, nullptr, lnf_g, lnf_b, xcur, nullptr);
}

// Round 16
// 848.168 us; speedup vs baseline: 1.1126x; 1.0376x over previous
//
#include <hip/hip_runtime.h>
#include <hip/hip_bf16.h>
#include <math.h>

#define DEVI __device__ __forceinline__

namespace {
constexpr int kL   = 1024;
constexpr int kDM  = 512;
constexpr int kDS  = 16;
constexpr int kDFF = 2048;
constexpr int kR   = 32;
constexpr int kDI  = 512;
constexpr int kB   = 16;
constexpr int kM   = kB * kL;     // 16384 rows
constexpr int kNC  = 16;          // scan chunks
constexpr int kCH  = kL / kNC;    // 64 steps per chunk
constexpr float kLOG2E = 1.4426950408889634f;
}

typedef __attribute__((ext_vector_type(8))) short short8;
typedef __attribute__((ext_vector_type(4))) float f32x4;

DEVI float silu_f(float x)     { return x / (1.f + __expf(-x)); }
DEVI float softplus_f(float x) { return fmaxf(x, 0.f) + log1pf(__expf(-fabsf(x))); }
DEVI float gelu_f(float x)     { return 0.5f * x * (1.f + erff(x * 0.70710678118654752f)); }

// raw hardware exp2 (v_exp_f32)
DEVI float fexp2(float x) {
    float r;
    asm("v_exp_f32 %0, %1" : "=v"(r) : "v"(x));
    return r;
}

DEVI unsigned short f2bf(float f) {
    unsigned int u = __float_as_uint(f);
    return (unsigned short)((u + 0x7fffu + ((u >> 16) & 1u)) >> 16);
}
DEVI float bf2f(unsigned short u) {
    return __uint_as_float(((unsigned int)u) << 16);
}
DEVI uint2 pack4(float4 v) {
    uint2 p;
    p.x = (unsigned int)f2bf(v.x) | ((unsigned int)f2bf(v.y) << 16);
    p.y = (unsigned int)f2bf(v.z) | ((unsigned int)f2bf(v.w) << 16);
    return p;
}

// log-depth power tree: qq[s] = r^(s+1), 15 muls, dependency depth 4
DEVI void powtree16(float r, float* qq) {
    qq[0] = r;
#pragma unroll
    for (int s = 1; s < 16; ++s) {
        int a = (s - 1) >> 1, b = (s - 1) - a;
        qq[s] = qq[a] * qq[b];
    }
}

typedef const __attribute__((address_space(1))) unsigned int* gas1;
typedef __attribute__((address_space(3))) unsigned int* las3;
DEVI void gload16(const unsigned short* g, unsigned short* l) {
    __builtin_amdgcn_global_load_lds((gas1)g, (las3)l, 16, 0, 0);
}

// ---------------------------------------------------------------------------
// One-shot weight conversion f32 -> bf16 (6 segments).
// ---------------------------------------------------------------------------
struct WCvtArgs { const float* src[6]; unsigned int end[6]; };

__global__ __launch_bounds__(256) void cvt_weights_k(
    WCvtArgs a, unsigned short* __restrict__ dst)
{
    unsigned int i = (blockIdx.x * 256 + threadIdx.x) * 4;
    if (i >= a.end[5]) return;
    int j = 0;
    while (i >= a.end[j]) ++j;
    unsigned int base = j ? a.end[j - 1] : 0;
    float4 v = *(const float4*)&a.src[j][i - base];
    *(uint2*)&dst[i] = pack4(v);
}

__global__ __launch_bounds__(256) void init_x_k(
    const float* __restrict__ x, float* __restrict__ xo,
    unsigned short* __restrict__ xb)
{
    size_t i = (size_t)(blockIdx.x * 256 + threadIdx.x) * 4;
    float4 v = *(const float4*)&x[i];
    *(float4*)&xo[i] = v;
    *(uint2*)&xb[i] = pack4(v);
}

// ---------------------------------------------------------------------------
// bf16 MFMA GEMM: 128 x BN, BK=32, 4 waves, double-buffered LDS with
// counted-vmcnt pipeline. EPI: 0 plain (CT), 1 bias+softplus (CT),
// 3 bias+gelu (bf16), 4 bias+add[bf16] (f32 out), 5 f32 + bf16 aux cols<32.
// ---------------------------------------------------------------------------
template <int EPI, int BN, typename CT>
__global__ __launch_bounds__(256) void gemm_bf16(
    const unsigned short* __restrict__ A, int lda, size_t zA,
    const unsigned short* __restrict__ W, size_t zW,
    CT* __restrict__ C, int ldc, size_t zC,
    const float* __restrict__ biasb, int zBias,
    const unsigned short* __restrict__ add,
    unsigned short* __restrict__ auxb, size_t zAux, int Kd)
{
    static_assert(BN == 64 || BN == 128, "");
    constexpr int NF = BN / 32;
    __shared__ alignas(16) unsigned short As[2][128 * 32];
    __shared__ alignas(16) unsigned short Ws[2][BN * 32];

    const int z = blockIdx.z;
    A += (size_t)z * zA; W += (size_t)z * zW; C += (size_t)z * zC;
    const float* bias = biasb ? biasb + (size_t)z * zBias : nullptr;
    unsigned short* aux = auxb ? auxb + (size_t)z * zAux : nullptr;

    const int gx = gridDim.x;
    int flat = blockIdx.y * gx + blockIdx.x;
    const int total = gx * gridDim.y;
    if ((total & 7) == 0) {
        int q = total >> 3;
        flat = (flat & 7) * q + (flat >> 3);
    }
    const int bx = flat % gx;
    const int by = flat / gx;

    const int tid  = threadIdx.x;
    const int lane = tid & 63;
    const int wv   = tid >> 6;
    const int wm   = wv >> 1;
    const int wn   = wv & 1;
    const int row0 = by * 128;
    const int col0 = bx * BN;

    f32x4 acc[4][NF];
#pragma unroll
    for (int m = 0; m < 4; ++m)
#pragma unroll
        for (int n = 0; n < NF; ++n) acc[m][n] = (f32x4){0.f, 0.f, 0.f, 0.f};

    const int sr  = tid >> 2;
    const int scw = (((tid & 3) ^ ((tid >> 3) & 3)) * 8);
    const unsigned short* Ag = A + (size_t)(row0 + sr) * lda + scw;
    const unsigned short* Wg = W + (size_t)(col0 + sr) * Kd + scw;

    auto stage = [&](int buf, int k0) {
        gload16(Ag + k0, &As[buf][tid * 8]);
        gload16(Ag + (size_t)64 * lda + k0, &As[buf][2048 + tid * 8]);
        gload16(Wg + k0, &Ws[buf][tid * 8]);
        if (BN == 128)
            gload16(Wg + (size_t)64 * Kd + k0, &Ws[buf][2048 + tid * 8]);
    };

    const int nt = Kd / 32;
    stage(0, 0);
    if (nt > 1) stage(1, 32);

    const int fr  = lane & 15;
    const int sw8 = (((lane >> 4) ^ ((fr >> 1) & 3)) * 8);

    for (int t = 0; t < nt; ++t) {
        const int cur = t & 1;
        if (t + 1 < nt) {
            if constexpr (BN == 128) asm volatile("s_waitcnt vmcnt(4)" ::: "memory");
            else                     asm volatile("s_waitcnt vmcnt(3)" ::: "memory");
        } else {
            asm volatile("s_waitcnt vmcnt(0)" ::: "memory");
        }
        __builtin_amdgcn_sched_barrier(0);
        __builtin_amdgcn_s_barrier();
        __builtin_amdgcn_sched_barrier(0);

        short8 af[4], bf[NF];
#pragma unroll
        for (int m = 0; m < 4; ++m)
            af[m] = *(const short8*)&As[cur][(wm * 64 + m * 16 + fr) * 32 + sw8];
#pragma unroll
        for (int n = 0; n < NF; ++n)
            bf[n] = *(const short8*)&Ws[cur][(wn * (BN / 2) + n * 16 + fr) * 32 + sw8];
        __builtin_amdgcn_s_setprio(1);
#pragma unroll
        for (int m = 0; m < 4; ++m)
#pragma unroll
            for (int n = 0; n < NF; ++n)
                acc[m][n] = __builtin_amdgcn_mfma_f32_16x16x32_bf16(
                    af[m], bf[n], acc[m][n], 0, 0, 0);
        __builtin_amdgcn_s_setprio(0);

        __builtin_amdgcn_sched_barrier(0);
        __builtin_amdgcn_s_barrier();
        __builtin_amdgcn_sched_barrier(0);
        if (t + 2 < nt) stage(cur, (t + 2) * 32);
    }

    const int cr = (lane >> 4) * 4;
#pragma unroll
    for (int m = 0; m < 4; ++m) {
#pragma unroll
        for (int n = 0; n < NF; ++n) {
            int cn = col0 + wn * (BN / 2) + n * 16 + fr;
#pragma unroll
            for (int r = 0; r < 4; ++r) {
                int rr = row0 + wm * 64 + m * 16 + cr + r;
                size_t idx = (size_t)rr * ldc + cn;
                float v = acc[m][n][r];
                if constexpr (EPI == 0) {
                    if constexpr (__is_same(CT, unsigned short)) C[idx] = f2bf(v);
                    else C[idx] = v;
                } else if constexpr (EPI == 1) {
                    float sp = softplus_f(v + bias[cn]);
                    if constexpr (__is_same(CT, unsigned short)) C[idx] = f2bf(sp);
                    else C[idx] = sp;
                } else if constexpr (EPI == 3) {
                    C[idx] = f2bf(gelu_f(v + bias[cn]));
                } else if constexpr (EPI == 4) {
                    C[idx] = v + bias[cn] + bf2f(add[idx]);
                } else {  // 5: f32 out + bf16 aux for cols < 32
                    C[idx] = v;
                    if (cn < 32) aux[(size_t)rr * 32 + cn] = f2bf(v);
                }
            }
        }
    }
}

// ---------------------------------------------------------------------------
// Sliding-window depthwise conv (K=4) + bias + silu.
// ---------------------------------------------------------------------------
__global__ __launch_bounds__(128) void conv_silu_k(
    const unsigned short* __restrict__ xz2, unsigned short* __restrict__ xcb,
    const float* __restrict__ wb, const float* __restrict__ biasb)
{
    const int task = blockIdx.x * 128 + threadIdx.x;
    const int g   = task & 63;
    const int c   = (task >> 6) & 31;
    const int b   = (task >> 11) & 15;
    const int dir = (task >> 15) & 1;
    const int d0  = g * 8;

    const unsigned short* xzd = xz2 + (size_t)dir * 1024 + (size_t)b * kL * 2048 + d0;
    unsigned short* xc = xcb + (size_t)dir * kM * kDI + (size_t)b * kL * kDI + d0;
    const float* w    = wb + (size_t)dir * 2048;
    const float* bias = biasb + (size_t)dir * 512;

    float wk[4][8];
#pragma unroll
    for (int k = 0; k < 4; ++k)
#pragma unroll
        for (int j = 0; j < 8; ++j)
            wk[k][j] = w[(d0 + j) * 4 + (dir ? 3 - k : k)];
    float bs[8];
#pragma unroll
    for (int j = 0; j < 8; ++j) bs[j] = bias[d0 + j];

    const int t0 = c * 32;
    const int rbase = dir ? t0 : t0 - 3;

    auto loadrow = [&](int t, float* o) {
        if (t < 0 || t >= kL) {
#pragma unroll
            for (int j = 0; j < 8; ++j) o[j] = 0.f;
            return;
        }
        uint4 p = *(const uint4*)&xzd[(size_t)t * 2048];
        o[0] = bf2f((unsigned short)(p.x & 0xffff));
        o[1] = bf2f((unsigned short)(p.x >> 16));
        o[2] = bf2f((unsigned short)(p.y & 0xffff));
        o[3] = bf2f((unsigned short)(p.y >> 16));
        o[4] = bf2f((unsigned short)(p.z & 0xffff));
        o[5] = bf2f((unsigned short)(p.z >> 16));
        o[6] = bf2f((unsigned short)(p.w & 0xffff));
        o[7] = bf2f((unsigned short)(p.w >> 16));
    };

    float x0[8], x1[8], x2[8];
    loadrow(rbase + 0, x0);
    loadrow(rbase + 1, x1);
    loadrow(rbase + 2, x2);

#pragma unroll 4
    for (int i = 0; i < 32; ++i) {
        float x3[8];
        loadrow(rbase + 3 + i, x3);
        unsigned short o[8];
#pragma unroll
        for (int j = 0; j < 8; ++j) {
            float v = bs[j];
            v = fmaf(wk[0][j], x0[j], v);
            v = fmaf(wk[1][j], x1[j], v);
            v = fmaf(wk[2][j], x2[j], v);
            v = fmaf(wk[3][j], x3[j], v);
            o[j] = f2bf(silu_f(v));
        }
        *(uint4*)&xc[(size_t)(t0 + i) * kDI] = *(uint4*)o;
#pragma unroll
        for (int j = 0; j < 8; ++j) { x0[j] = x1[j]; x1[j] = x2[j]; x2[j] = x3[j]; }
    }
}

// ---------------------------------------------------------------------------
// Chunked selective scan (NC=16, 64-step chunks), both dirs (blockIdx.y).
// B staged to LDS once per block. Guarded geometric fast path (one v_exp +
// 15-mul power tree per step; exact-16-exp fallback).
// ---------------------------------------------------------------------------
__global__ __launch_bounds__(256) void scan_chunk(
    const unsigned short* __restrict__ dtb2, const unsigned short* __restrict__ xcb2,
    const float* __restrict__ dbl2, const float* __restrict__ A_logb,
    float* __restrict__ S2, float* __restrict__ sdt2)
{
    int dir = blockIdx.y;
    const unsigned short* dtb = dtb2 + (size_t)dir * kM * kDI;
    const unsigned short* xcb = xcb2 + (size_t)dir * kM * kDI;
    const float* dbl = dbl2 + (size_t)dir * kM * 64;
    const float* A_log = A_logb + (size_t)dir * 8192;
    float* S   = S2 + (size_t)dir * (kB * kNC * kDS * kDI);
    float* sdt = sdt2 + (size_t)dir * (kB * kNC * kDI);

    int blk  = blockIdx.x;                 // kB * kNC * 2 = 512
    int dblk = blk & 1;
    int c    = (blk >> 1) & (kNC - 1);
    int b    = blk >> 5;
    int d    = dblk * 256 + threadIdx.x;

    __shared__ float blds[kCH][16];
    {
        int i = threadIdx.x >> 2, q = (threadIdx.x & 3) * 4;
        int t = dir ? (kL - 1 - (c * kCH + i)) : (c * kCH + i);
        *(float4*)&blds[i][q] =
            *(const float4*)&dbl[(size_t)(b * kL + t) * 64 + kR + q];
    }
    __syncthreads();

    const float* al = A_log + d * kDS;
    float A2[16];
#pragma unroll
    for (int s = 0; s < 16; ++s) A2[s] = -__expf(al[s]) * kLOG2E;

    bool fast = true;
#pragma unroll
    for (int s = 1; s < 16; ++s)
        fast = fast && (fabsf(A2[s] - A2[0] * (float)(s + 1)) <= 1e-4f * fabsf(A2[s]));

    float h[16];
#pragma unroll
    for (int s = 0; s < 16; ++s) h[s] = 0.f;
    float sum = 0.f;

    if (fast) {
        const float A0 = A2[0];
#pragma unroll 2
        for (int i = 0; i < kCH; ++i) {
            int p   = c * kCH + i;
            int t   = dir ? (kL - 1 - p) : p;
            int row = b * kL + t;
            float dt = bf2f(dtb[(size_t)row * kDI + d]);
            float xv = bf2f(xcb[(size_t)row * kDI + d]);
            sum += dt;
            float dx = dt * xv;
            float qq[16];
            powtree16(fexp2(dt * A0), qq);
            const float4* bp = (const float4*)&blds[i][0];
            float4 b0 = bp[0], b1 = bp[1], b2 = bp[2], b3 = bp[3];
            float Bv[16] = {b0.x, b0.y, b0.z, b0.w, b1.x, b1.y, b1.z, b1.w,
                            b2.x, b2.y, b2.z, b2.w, b3.x, b3.y, b3.z, b3.w};
#pragma unroll
            for (int s = 0; s < 16; ++s)
                h[s] = fmaf(qq[s], h[s], dx * Bv[s]);
        }
    } else {
#pragma unroll 2
        for (int i = 0; i < kCH; ++i) {
            int p   = c * kCH + i;
            int t   = dir ? (kL - 1 - p) : p;
            int row = b * kL + t;
            float dt = bf2f(dtb[(size_t)row * kDI + d]);
            float xv = bf2f(xcb[(size_t)row * kDI + d]);
            sum += dt;
            float dx = dt * xv;
            const float4* bp = (const float4*)&blds[i][0];
            float4 b0 = bp[0], b1 = bp[1], b2 = bp[2], b3 = bp[3];
            float Bv[16] = {b0.x, b0.y, b0.z, b0.w, b1.x, b1.y, b1.z, b1.w,
                            b2.x, b2.y, b2.z, b2.w, b3.x, b3.y, b3.z, b3.w};
#pragma unroll
            for (int s = 0; s < 16; ++s) {
                float q = fexp2(dt * A2[s]);
                h[s] = fmaf(q, h[s], dx * Bv[s]);
            }
        }
    }
    size_t base = (size_t)(b * kNC + c) * kDS * kDI + d;
#pragma unroll
    for (int s = 0; s < 16; ++s) S[base + s * kDI] = h[s];
    sdt[(size_t)(b * kNC + c) * kDI + d] = sum;
}

// ---------------------------------------------------------------------------
// Carry scan: one thread per (b,d,s); h0 written in-place over S. 16 steps.
// ---------------------------------------------------------------------------
__global__ __launch_bounds__(256) void scan_carry(
    float* __restrict__ S2, const float* __restrict__ sdt2,
    const float* __restrict__ A_logb)
{
    int dir = blockIdx.y;
    float* S = S2 + (size_t)dir * (kB * kNC * kDS * kDI);
    const float* sdt = sdt2 + (size_t)dir * (kB * kNC * kDI);
    const float* A_log = A_logb + (size_t)dir * 8192;

    int g = blockIdx.x * 256 + threadIdx.x;   // 0..131071
    int d = g & (kDI - 1);
    int s = (g >> 9) & 15;
    int b = g >> 13;

    float A2 = -__expf(A_log[d * kDS + s]) * kLOG2E;
    float h = 0.f;
#pragma unroll
    for (int c = 0; c < kNC; ++c) {
        size_t base = ((size_t)(b * kNC + c) * kDS + s) * kDI + d;
        float sv = S[base];
        float sd = sdt[(size_t)(b * kNC + c) * kDI + d];
        S[base] = h;                          // h0 in-place
        h = fmaf(fexp2(sd * A2), h, sv);
    }
}

// ---------------------------------------------------------------------------
// Emit scan: B/C staged to LDS; guarded geometric fast path. 64-step chunks.
// ---------------------------------------------------------------------------
__global__ __launch_bounds__(256) void scan_emit(
    const unsigned short* __restrict__ dtb2, const unsigned short* __restrict__ xcb2,
    const float* __restrict__ dbl2, const float* __restrict__ A_logb,
    const float* __restrict__ h0v2, const float* __restrict__ Dpb,
    const unsigned short* __restrict__ xz2, unsigned short* __restrict__ yb2)
{
    int dir = blockIdx.y;
    const unsigned short* dtb = dtb2 + (size_t)dir * kM * kDI;
    const unsigned short* xcb = xcb2 + (size_t)dir * kM * kDI;
    const float* dbl = dbl2 + (size_t)dir * kM * 64;
    const float* A_log = A_logb + (size_t)dir * 8192;
    const float* h0v = h0v2 + (size_t)dir * (kB * kNC * kDS * kDI);
    const float* Dp = Dpb + (size_t)dir * 512;
    const unsigned short* zg = xz2 + (size_t)dir * 1024 + 512;
    unsigned short* yb = yb2 + (size_t)dir * kM * kDI;

    int blk  = blockIdx.x;
    int dblk = blk & 1;
    int c    = (blk >> 1) & (kNC - 1);
    int b    = blk >> 5;
    int d    = dblk * 256 + threadIdx.x;

    __shared__ float bclds[kCH][32];
    {
        int i0 = threadIdx.x >> 3, q = (threadIdx.x & 7) * 4;
#pragma unroll
        for (int rr = 0; rr < 2; ++rr) {
            int i = i0 + rr * 32;
            int t = dir ? (kL - 1 - (c * kCH + i)) : (c * kCH + i);
            *(float4*)&bclds[i][q] =
                *(const float4*)&dbl[(size_t)(b * kL + t) * 64 + kR + q];
        }
    }
    __syncthreads();

    const float* al = A_log + d * kDS;
    float A2[16];
#pragma unroll
    for (int s = 0; s < 16; ++s) A2[s] = -__expf(al[s]) * kLOG2E;
    float Dd = Dp[d];

    bool fast = true;
#pragma unroll
    for (int s = 1; s < 16; ++s)
        fast = fast && (fabsf(A2[s] - A2[0] * (float)(s + 1)) <= 1e-4f * fabsf(A2[s]));

    size_t hbase = (size_t)(b * kNC + c) * kDS * kDI + d;
    float h[16];
#pragma unroll
    for (int s = 0; s < 16; ++s) h[s] = h0v[hbase + s * kDI];

    if (fast) {
        const float A0 = A2[0];
#pragma unroll 2
        for (int i = 0; i < kCH; ++i) {
            int p   = c * kCH + i;
            int t   = dir ? (kL - 1 - p) : p;
            int row = b * kL + t;
            float dt = bf2f(dtb[(size_t)row * kDI + d]);
            float xv = bf2f(xcb[(size_t)row * kDI + d]);
            float dx = dt * xv;
            float qq[16];
            powtree16(fexp2(dt * A0), qq);
            const float4* bp = (const float4*)&bclds[i][0];
            const float4* cp = (const float4*)&bclds[i][16];
            float4 b0 = bp[0], b1 = bp[1], b2 = bp[2], b3 = bp[3];
            float4 c0 = cp[0], c1 = cp[1], c2 = cp[2], c3 = cp[3];
            float Bv[16] = {b0.x, b0.y, b0.z, b0.w, b1.x, b1.y, b1.z, b1.w,
                            b2.x, b2.y, b2.z, b2.w, b3.x, b3.y, b3.z, b3.w};
            float Cv[16] = {c0.x, c0.y, c0.z, c0.w, c1.x, c1.y, c1.z, c1.w,
                            c2.x, c2.y, c2.z, c2.w, c3.x, c3.y, c3.z, c3.w};
            float y = 0.f;
#pragma unroll
            for (int s = 0; s < 16; ++s) {
                h[s] = fmaf(qq[s], h[s], dx * Bv[s]);
                y = fmaf(h[s], Cv[s], y);
            }
            y += xv * Dd;
            float zv = bf2f(zg[(size_t)row * 2048 + d]);
            yb[(size_t)row * kDI + d] = f2bf(y * silu_f(zv));
        }
    } else {
#pragma unroll 2
        for (int i = 0; i < kCH; ++i) {
            int p   = c * kCH + i;
            int t   = dir ? (kL - 1 - p) : p;
            int row = b * kL + t;
            float dt = bf2f(dtb[(size_t)row * kDI + d]);
            float xv = bf2f(xcb[(size_t)row * kDI + d]);
            float dx = dt * xv;
            const float4* bp = (const float4*)&bclds[i][0];
            const float4* cp = (const float4*)&bclds[i][16];
            float4 b0 = bp[0], b1 = bp[1], b2 = bp[2], b3 = bp[3];
            float4 c0 = cp[0], c1 = cp[1], c2 = cp[2], c3 = cp[3];
            float Bv[16] = {b0.x, b0.y, b0.z, b0.w, b1.x, b1.y, b1.z, b1.w,
                            b2.x, b2.y, b2.z, b2.w, b3.x, b3.y, b3.z, b3.w};
            float Cv[16] = {c0.x, c0.y, c0.z, c0.w, c1.x, c1.y, c1.z, c1.w,
                            c2.x, c2.y, c2.z, c2.w, c3.x, c3.y, c3.z, c3.w};
            float y = 0.f;
#pragma unroll
            for (int s = 0; s < 16; ++s) {
                float q = fexp2(dt * A2[s]);
                h[s] = fmaf(q, h[s], dx * Bv[s]);
                y = fmaf(h[s], Cv[s], y);
            }
            y += xv * Dd;
            float zv = bf2f(zg[(size_t)row * 2048 + d]);
            yb[(size_t)row * kDI + d] = f2bf(y * silu_f(zv));
        }
    }
}

// ---------------------------------------------------------------------------
// LayerNorm over rows of 512; optional 2 bf16 add-inputs; f32 and/or bf16 out.
// ---------------------------------------------------------------------------
__global__ __launch_bounds__(128) void ln_k(
    const float* __restrict__ in, const unsigned short* __restrict__ a0,
    const unsigned short* __restrict__ a1,
    const float* __restrict__ g, const float* __restrict__ bb,
    float* __restrict__ out, unsigned short* __restrict__ outbf)
{
    int row = blockIdx.x;
    int tid = threadIdx.x;
    size_t off = (size_t)row * kDM + tid * 4;
    float4 v = *(const float4*)&in[off];
    if (a0) {
        uint2 u0 = *(const uint2*)&a0[off];
        uint2 u1 = *(const uint2*)&a1[off];
        v.x += bf2f((unsigned short)(u0.x & 0xffff)) + bf2f((unsigned short)(u1.x & 0xffff));
        v.y += bf2f((unsigned short)(u0.x >> 16))    + bf2f((unsigned short)(u1.x >> 16));
        v.z += bf2f((unsigned short)(u0.y & 0xffff)) + bf2f((unsigned short)(u1.y & 0xffff));
        v.w += bf2f((unsigned short)(u0.y >> 16))    + bf2f((unsigned short)(u1.y >> 16));
    }
    float s1 = v.x + v.y + v.z + v.w;
    float s2 = v.x * v.x + v.y * v.y + v.z * v.z + v.w * v.w;
#pragma unroll
    for (int o = 32; o >= 1; o >>= 1) {
        s1 += __shfl_xor(s1, o);
        s2 += __shfl_xor(s2, o);
    }
    __shared__ float red[4];
    if ((tid & 63) == 0) { red[(tid >> 6) * 2] = s1; red[(tid >> 6) * 2 + 1] = s2; }
    __syncthreads();
    s1 = red[0] + red[2];
    s2 = red[1] + red[3];
    float mu  = s1 * (1.f / kDM);
    float var = s2 * (1.f / kDM) - mu * mu;
    float rs  = rsqrtf(var + 1e-5f);
    int cn = tid * 4;
    float4 gv = *(const float4*)&g[cn];
    float4 bv = *(const float4*)&bb[cn];
    float4 o;
    o.x = (v.x - mu) * rs * gv.x + bv.x;
    o.y = (v.y - mu) * rs * gv.y + bv.y;
    o.z = (v.z - mu) * rs * gv.z + bv.z;
    o.w = (v.w - mu) * rs * gv.w + bv.w;
    if (out)
        *(float4*)&out[off] = o;
    if (outbf)
        *(uint2*)&outbf[off] = pack4(o);
}

// ---------------------------------------------------------------------------
extern "C" void kernel_launch(void* const* d_in, const int* in_sizes, int n_in,
                              void* d_out, int out_size, void* d_ws, size_t ws_size,
                              hipStream_t stream)
{
    const float* x_in    = (const float*)d_in[0];
    const float* in_w    = (const float*)d_in[1];
    const float* conv_w  = (const float*)d_in[2];
    const float* conv_b  = (const float*)d_in[3];
    const float* xproj_w = (const float*)d_in[4];
    const float* dt_w    = (const float*)d_in[5];
    const float* dt_b    = (const float*)d_in[6];
    const float* A_log   = (const float*)d_in[7];
    const float* Dp      = (const float*)d_in[8];
    const float* out_w   = (const float*)d_in[9];
    const float* ff_w1   = (const float*)d_in[10];
    const float* ff_b1   = (const float*)d_in[11];
    const float* ff_w2   = (const float*)d_in[12];
    const float* ff_b2   = (const float*)d_in[13];
    const float* ln1_g   = (const float*)d_in[14];
    const float* ln1_b   = (const float*)d_in[15];
    const float* ln2_g   = (const float*)d_in[16];
    const float* ln2_b   = (const float*)d_in[17];
    const float* lnf_g   = (const float*)d_in[18];
    const float* lnf_b   = (const float*)d_in[19];

    float* ws = (float*)d_ws;
    unsigned short* wsb = (unsigned short*)d_ws;

    // bf16 weights (bf16-elem offsets into wsb)
    unsigned short* wb_in  = wsb;                 // in_w   [0, 2097152)
    unsigned short* wb_xp  = wsb + 2097152;       // xproj  [.., 2228224)
    unsigned short* wb_out = wsb + 2228224;       // out_w  [.., 3276800)
    unsigned short* wb_f1  = wsb + 3276800;       // ff_w1  [.., 5373952)
    unsigned short* wb_f2  = wsb + 5373952;       // ff_w2  [.., 7471104)
    unsigned short* wb_dt  = wsb + 7471104;       // dt_w   [.., 7536640)

    constexpr size_t A0 = 3768320;                // f32-word offset of arena
    unsigned short* xbf  = (unsigned short*)(ws + A0);                  // 4.19M w
    unsigned short* xz2  = (unsigned short*)(ws + A0 + 4194304);        // 16.78M w
    unsigned short* xcb2 = (unsigned short*)(ws + A0 + 20971520);       // 8.39M w
    unsigned short* yb2  = (unsigned short*)(ws + A0 + 29360128);       // 8.39M w
    float*          Sb2  = ws + A0 + 37748736;                          // S/h0 (now 16.8MB)
    unsigned short* dtb2 = (unsigned short*)(ws + A0 + 46137344);       // 8.39M w
    float*          dbl2 = ws + A0 + 54525952;                          // 2.10M w
    unsigned short* dtin2= (unsigned short*)(ws + A0 + 56623104);       // 0.52M w
    float*          sdt2 = ws + A0 + 57147392;                          // 0.52M w
    // out-proj bf16 outputs alias scan scratch (S/h0 dead after scan_emit)
    unsigned short* o2   = (unsigned short*)(ws + A0 + 37748736);       // 8M w as bf16
    // FFN-phase aliases (mamba arena dead)
    unsigned short* xnbf = (unsigned short*)(ws + A0 + 8388608);        // 4.19M w
    unsigned short* Hb   = (unsigned short*)(ws + A0 + 12582912);       // 16.78M w
    float*          t2   = ws + A0 + 29360128;                          // 8.39M w

    float* xcur = (float*)d_out;
    dim3 thr(256);

    WCvtArgs wa;
    wa.src[0] = in_w;    wa.end[0] = 2097152;
    wa.src[1] = xproj_w; wa.end[1] = 2228224;
    wa.src[2] = out_w;   wa.end[2] = 3276800;
    wa.src[3] = ff_w1;   wa.end[3] = 5373952;
    wa.src[4] = ff_w2;   wa.end[4] = 7471104;
    wa.src[5] = dt_w;    wa.end[5] = 7536640;
    cvt_weights_k<<<dim3(7536640 / 1024), thr, 0, stream>>>(wa, wsb);
    init_x_k<<<dim3(8192), thr, 0, stream>>>(x_in, xcur, xbf);

    for (int e = 0; e < 2; ++e) {
        // in-proj (both dirs fused): (kM x 512) @ (2048 x 512)^T -> xz2 bf16
        gemm_bf16<0, 128, unsigned short><<<dim3(16, 128), thr, 0, stream>>>(
            xbf, 512, 0, wb_in + (size_t)e * 1048576, 0, xz2, 2048, 0,
            nullptr, 0, nullptr, nullptr, 0, 512);
        // conv + silu (both dirs, sliding window)
        conv_silu_k<<<dim3(512), dim3(128), 0, stream>>>(
            xz2, xcb2, conv_w + (size_t)e * 4096, conv_b + (size_t)e * 1024);
        // x-proj (both dirs): -> dbl f32 + dtin bf16
        gemm_bf16<5, 64, float><<<dim3(1, 128, 2), thr, 0, stream>>>(
            xcb2, 512, (size_t)kM * 512, wb_xp + (size_t)e * 65536, 32768,
            dbl2, 64, (size_t)kM * 64, nullptr, 0, nullptr,
            dtin2, (size_t)kM * 32, 512);
        // dt-proj (both dirs): softplus -> dtb2 bf16
        gemm_bf16<1, 128, unsigned short><<<dim3(4, 128, 2), thr, 0, stream>>>(
            dtin2, 32, (size_t)kM * 32, wb_dt + (size_t)e * 32768, 16384,
            dtb2, 512, (size_t)kM * 512, dt_b + (size_t)e * 1024, 512,
            nullptr, nullptr, 0, 32);
        // scans (both dirs); NC=16 x 64-step chunks
        scan_chunk<<<dim3(kB * kNC * 2, 2), thr, 0, stream>>>(
            dtb2, xcb2, dbl2, A_log + (size_t)e * 16384, Sb2, sdt2);
        scan_carry<<<dim3(512, 2), thr, 0, stream>>>(
            Sb2, sdt2, A_log + (size_t)e * 16384);
        scan_emit<<<dim3(kB * kNC * 2, 2), thr, 0, stream>>>(
            dtb2, xcb2, dbl2, A_log + (size_t)e * 16384, Sb2,
            Dp + (size_t)e * 1024, xz2, yb2);
        // out-proj (both dirs) -> o2 bf16 (separate buffers; LN1 adds)
        gemm_bf16<0, 128, unsigned short><<<dim3(4, 128, 2), thr, 0, stream>>>(
            yb2, 512, (size_t)kM * 512, wb_out + (size_t)e * 524288, 262144,
            o2, 512, (size_t)kM * 512, nullptr, 0, nullptr, nullptr, 0, 512);
        // LN1: normalize (xcur + o0 + o1) -> xnbf bf16 only
        ln_k<<<dim3(kM), dim3(128), 0, stream>>>(
            xcur, o2, o2 + (size_t)kM * 512,
            ln1_g + e * kDM, ln1_b + e * kDM, nullptr, xnbf);
        // FFN1: gelu(xnbf @ w1^T + b1) -> Hb bf16
        gemm_bf16<3, 128, unsigned short><<<dim3(16, 128), thr, 0, stream>>>(
            xnbf, 512, 0, wb_f1 + (size_t)e * 1048576, 0, Hb, 2048, 0,
            ff_b1 + (size_t)e * kDFF, 0, nullptr, nullptr, 0, 512);
        // FFN2: Hb @ w2^T + b2 + xnbf -> t2 f32
        gemm_bf16<4, 128, float><<<dim3(4, 128), thr, 0, stream>>>(
            Hb, 2048, 0, wb_f2 + (size_t)e * 1048576, 0, t2, 512, 0,
            ff_b2 + (size_t)e * kDM, 0, xnbf, nullptr, 0, 2048);
        // LN2 -> xcur (+ bf16 snapshot for next layer)
        ln_k<<<dim3(kM), dim3(128), 0, stream>>>(
            t2, nullptr, nullptr, ln2_g + e * kDM, ln2_b + e * kDM, xcur,
            e == 0 ? xbf : nullptr);
    }
    ln_k<<<dim3(kM), dim3(128), 0, stream>>>(
        xcur, nullptr, nullptr, lnf_g, lnf_b, xcur, nullptr);
}